// Round 9
// baseline (1464.670 us; speedup 1.0000x reference)
//
#include <hip/hip_runtime.h>

typedef _Float16 f16;
typedef _Float16 f16x4 __attribute__((ext_vector_type(4)));
typedef _Float16 f16x8 __attribute__((ext_vector_type(8)));
typedef float f32x2 __attribute__((ext_vector_type(2)));
typedef float f32x4 __attribute__((ext_vector_type(4)));
typedef float f32x16 __attribute__((ext_vector_type(16)));

#define MFMA16(a, b, c) __builtin_amdgcn_mfma_f32_16x16x32_f16((a), (b), (c), 0, 0, 0)
#define MFMA32(a, b, c) __builtin_amdgcn_mfma_f32_32x32x16_f16((a), (b), (c), 0, 0, 0)

__device__ __forceinline__ float rcp_(float x) { return __builtin_amdgcn_rcpf(x); }
__device__ __forceinline__ float sigm(float v) { return rcp_(1.0f + __expf(-v)); }
__device__ __forceinline__ float tanh_(float v) { return 1.0f - 2.0f * rcp_(__expf(2.0f * v) + 1.0f); }
__device__ __forceinline__ float exp2_(float x) { return __builtin_amdgcn_exp2f(x); }

// ============ Kernel A: persistent ConvLSTM recurrence (32x32x16 MFMA) ========
// R15 vs R3/R9 (best verified: rec 588, MfmaUtil 43): switch the matrix work to
// v_mfma_f32_32x32x16_f16 (1015 vs 885 FLOP/cyc per SIMD, -24% matrix-pipe
// time). R8's lesson: register budget is a cliff -> keep TWO groups.
//  * Wave tile M=64 (2 x 32-row tiles) x N=32 (n = lane&31 = sl*16+pos over the
//    wave's 2 samples). K = 320: 18 h-steps (tap-half-cells of 16 ch) + 2
//    x-steps (k=tap*3+ic, k27=bias, k28-31 zero-weighted padding).
//  * A-frags: Ah32[18][2] (144 regs) + Ax32[2][2] (16) = 160 (was 176).
//    acc = 2 x f32x16 (32). cst[2][2][4]. ~235 regs, 2 waves/SIMD.
//  * B-frag: 1 ds_read_b128 per h-step feeds BOTH m-tiles. x-frag: 8 scalar
//    LDS reads via packed byte-offset table (pk0/pk1, 4 regs).
//  * Two-group interleave as R3; group B's GEMM is split per-mt (re-reads
//    B-frags) so it refills acc quads freed by group A's updates.
//  * Fragment layouts: C/D row=(reg&3)+8*(reg>>2)+4*(lane>>5), col=lane&31
//    (HW-verified); A row=lane&31 / B col=lane&31, k=(lane>>5)*8+j (K-doubling
//    pattern, analogous to the verified 16x16x32 mapping used before).
//
// Arena: hpad[2] [4 b][36 cell][80 B] 0..23040 (cell 80 B, sample 2880 B)
//        xpad[2] [4 b][36 cell][8 B]  23040..25344.  2 arenas = 50688 B.
#define LOG2E 1.4426950408889634f
#define HCELL 80
#define HSAMP 2880
#define HBUFB 11520
#define XP0 23040
#define XBUFB 1152
#define AR 25344
#define WSO 25344
#define SMEMA 50688
#define NPAIR 4096
#define GRID_REC 512

extern "C" __global__ __launch_bounds__(256, 2)
void hwq_rec(const float* __restrict__ gx, const float* __restrict__ ghour,
             const float* __restrict__ gcw, const float* __restrict__ gcb,
             const float* __restrict__ ghw1, const float* __restrict__ ghb1,
             const float* __restrict__ ghw2, const float* __restrict__ ghb2,
             f16* __restrict__ wz)
{
  __shared__ __align__(16) char smem[SMEMA];
  const int tid = threadIdx.x;
  const int lane = tid & 63;
  const int wv = tid >> 6;
  const int mg = wv & 1;                // M-half: m in [mg*64, mg*64+64)
  const int ng = wv >> 1;               // N-half: samples ng*2, ng*2+1
  const int lr = lane & 15;             // position
  const int l31 = lane & 31;
  const int hi = lane >> 5;             // K-half within a 16-step
  const int sl_ = (lane >> 4) & 1;      // sample-within-n (n = sl*16+pos)
  const int TOFF[9] = {0, 1, 2, 6, 7, 8, 12, 13, 14};
  const int pp0 = (lr >> 2) * 6 + (lr & 3);

  // ---- prologue 1: Ax32 (x+bias A-frags) gathered directly from global ----
  f16x8 Ax32[2][2];                     // [k-step][mt]
  {
    #pragma unroll
    for (int mt = 0; mt < 2; ++mt) {
      int m = mg * 64 + mt * 32 + l31;
      int oc = ((m & 3) << 5) + (m >> 2);
      float sc = ((m & 3) == 3) ? (2.0f * LOG2E) : (-LOG2E);
      #pragma unroll
      for (int s = 0; s < 2; ++s) {
        f16x8 f;
        #pragma unroll
        for (int j = 0; j < 8; ++j) {
          int k = s * 16 + hi * 8 + j;
          float v = 0.0f;
          if (k < 27) { int tp = (k * 11) >> 5; v = sc * gcw[oc * 315 + (k - 3 * tp) * 9 + tp]; }
          else if (k == 27) v = sc * gcb[oc];
          f[j] = (f16)v;
        }
        Ax32[s][mt] = f;
      }
    }
  }
  // packed x-frag byte-offset tables (8 offsets x 8bit per k-step)
  unsigned long long pk0 = 0ULL, pk1 = 0ULL;
  {
    #pragma unroll
    for (int j = 0; j < 8; ++j) {
      #pragma unroll
      for (int s = 0; s < 2; ++s) {
        int k = s * 16 + hi * 8 + j;
        int off = 0;
        if (k < 27) { int tp = (k * 11) >> 5; off = TOFF[tp] * 8 + (k - 3 * tp) * 2; }
        else if (k == 27) off = 62;       // center-cell bias flag (pp0+7)*8+6
        if (s) pk1 |= (unsigned long long)off << (8 * j);
        else   pk0 |= (unsigned long long)off << (8 * j);
      }
    }
  }
  // ---- prologue 2: Ah32 via 4 staged 32-row chunks (chunk == m-tile) ----
  f16x8 Ah32[18][2];
  {
    f16* wst = (f16*)(smem + WSO);   // [32 row][288 = ch*9+tap]
    #pragma unroll
    for (int c = 0; c < 4; ++c) {
      for (int i = tid; i < 9216; i += 256) {
        int mrow = i / 288, rem = i - mrow * 288;
        int m = c * 32 + mrow;
        int oc = ((m & 3) << 5) + (m >> 2);
        float sc = ((m & 3) == 3) ? (2.0f * LOG2E) : (-LOG2E);
        wst[i] = (f16)(sc * gcw[oc * 315 + 27 + rem]);
      }
      __syncthreads();
      if ((c >> 1) == mg) {
        int mt = c & 1;
        #pragma unroll
        for (int s = 0; s < 18; ++s) {
          f16x8 f;
          #pragma unroll
          for (int j = 0; j < 8; ++j)
            f[j] = wst[l31 * 288 + ((s & 1) * 16 + hi * 8 + j) * 9 + (s >> 1)];
          Ah32[s][mt] = f;
        }
      }
      __syncthreads();
    }
  }
  // ---- prologue 3: zero BOTH arenas; bias flags in all 4 xpads ----
  {
    float* za = (float*)smem;
    for (int i = tid; i < 12672; i += 256) za[i] = 0.0f;   // 50688 B
    __syncthreads();
    {
      int ar = tid >> 7, xb = (tid >> 6) & 1, b = (tid >> 4) & 3, p = tid & 15;
      int cell = ((p >> 2) + 1) * 6 + (p & 3) + 1;
      *(f16*)(smem + ar * AR + XP0 + xb * XBUFB + b * 288 + cell * 8 + 6) = (f16)1.0f;
    }
    __syncthreads();
  }

  // ---- hot-loop bases ----
  const int hb32  = (ng * 2 + sl_) * HSAMP + pp0 * HCELL + hi * 16;
  const int xpb32 = XP0 + (ng * 2 + sl_) * 288 + pp0 * 8;
  const int wb32  = (ng * 2 + sl_) * HSAMP + (pp0 + 7) * HCELL + (mg * 16 + hi) * 2;
  const int TO32[18] = {0, 32, 80, 112, 160, 192, 480, 512, 560, 592,
                        640, 672, 960, 992, 1040, 1072, 1120, 1152};
  const bool stg = tid < 192;
  const int sb = tid / 48, srem = tid - sb * 48;
  const int sp = srem & 15, sic = srem >> 4;
  const int xdst = XP0 + sb * 288 + (((sp >> 2) + 1) * 6 + (sp & 3) + 1) * 8 + sic * 2;
  const int zb_ = tid >> 6, zc16 = (tid >> 2) & 15, zpart = tid & 3;
  const int zaddr = zb_ * HSAMP + ((zc16 >> 2) * 6 + (zc16 & 3) + 7) * HCELL + zpart * 16;

#define BFRAG(ab, s) (*(const f16x8*)(smem + (ab) + rb + hb32 + TO32[s]))
#define XFRAG(bf, ab, pkv) { \
    _Pragma("unroll") for (int j = 0; j < 8; ++j) \
      bf[j] = *(const f16*)(smem + (ab) + xrb + xpb32 + (int)(((pkv) >> (8 * j)) & 255ULL)); }

// both m-tiles, 20 B-frags, 40 MFMA (acc0/acc1 pre-zeroed)
#define GEMM_PAIR(ab) { \
    _Pragma("unroll") for (int s = 0; s < 18; ++s) { \
      f16x8 bf = BFRAG(ab, s); \
      acc0 = MFMA32(Ah32[s][0], bf, acc0); acc1 = MFMA32(Ah32[s][1], bf, acc1); } \
    { f16x8 bf; XFRAG(bf, ab, pk0); \
      acc0 = MFMA32(Ax32[0][0], bf, acc0); acc1 = MFMA32(Ax32[0][1], bf, acc1); } \
    { f16x8 bf; XFRAG(bf, ab, pk1); \
      acc0 = MFMA32(Ax32[1][0], bf, acc0); acc1 = MFMA32(Ax32[1][1], bf, acc1); } }

// single m-tile into av (pre-zeroed), 20 B-frags, 20 MFMA
#define GEMM_MT(ab, av, mt) { \
    _Pragma("unroll") for (int s = 0; s < 18; ++s) { \
      f16x8 bf = BFRAG(ab, s); av = MFMA32(Ah32[s][mt], bf, av); } \
    { f16x8 bf; XFRAG(bf, ab, pk0); av = MFMA32(Ax32[0][mt], bf, av); } \
    { f16x8 bf; XFRAG(bf, ab, pk1); av = MFMA32(Ax32[1][mt], bf, av); } }

// cell updates for one m-tile from f32x16 acc. reg r = gate + 4q;
// ch = mg*16 + mt*8 + 2q + hi; write h to other buffer.
#define UPD4_L(g, ab, av, mt) \
    _Pragma("unroll") for (int q = 0; q < 4; ++q) { \
      float Ei = exp2_(av[4 * q + 0]); \
      float Ef = exp2_(av[4 * q + 1]); \
      float Eo = exp2_(av[4 * q + 2]); \
      float Eg = exp2_(av[4 * q + 3]); \
      float fg = rcp_(1.0f + Ef); \
      float pq = rcp_((1.0f + Ei) * (1.0f + Eg)); \
      float cn = fmaf(fg, cst[g][mt][q], (2.0f * LOG2E) * ((Eg - 1.0f) * pq)); \
      cst[g][mt][q] = cn; \
      float Ec = exp2_(cn); \
      *(f16*)(smem + (ab) + wbuf + wb32 + (mt) * 16 + q * 4) = \
          (f16)((Ec - 1.0f) * rcp_((1.0f + Eo) * (1.0f + Ec))); }

#define UPD4_G(g, bgv, av, mt) \
    _Pragma("unroll") for (int q = 0; q < 4; ++q) { \
      float Ei = exp2_(av[4 * q + 0]); \
      float Ef = exp2_(av[4 * q + 1]); \
      float Eo = exp2_(av[4 * q + 2]); \
      float Eg = exp2_(av[4 * q + 3]); \
      float fg = rcp_(1.0f + Ef); \
      float pq = rcp_((1.0f + Ei) * (1.0f + Eg)); \
      float cn = fmaf(fg, cst[g][mt][q], (2.0f * LOG2E) * ((Eg - 1.0f) * pq)); \
      float Ec = exp2_(cn); \
      wz[(size_t)((bgv) + ng * 2 + sl_) * 544 + (mg * 16 + (mt) * 8 + 2 * q + hi) * 16 + lr] = \
          (f16)((Ec - 1.0f) * rcp_((1.0f + Eo) * (1.0f + Ec))); }

  for (int pi = 0; pi < 8; ++pi) {
    const int pr = (blockIdx.x << 3) + pi;
    const int bgA = pr << 3;          // samples bgA..bgA+3
    const int bgB = bgA + 4;
    const float* xsrcA = gx + (size_t)(bgA + sb) * 576 + srem;
    const float* xsrcB = gx + (size_t)(bgB + sb) * 576 + srem;

    // pair re-init: zero buf0 interiors (h0 = 0), stage xpad0(t=0), cst = 0
    {
      f32x2 z2 = {0.f, 0.f};
      *(f32x2*)(smem + zaddr) = z2;
      *(f32x2*)(smem + zaddr + 8) = z2;
      *(f32x2*)(smem + AR + zaddr) = z2;
      *(f32x2*)(smem + AR + zaddr + 8) = z2;
    }
    if (stg) {
      *(f16*)(smem + xdst) = (f16)xsrcA[0];
      *(f16*)(smem + AR + xdst) = (f16)xsrcB[0];
    }
    float cst[2][2][4];
    #pragma unroll
    for (int g = 0; g < 2; ++g)
      #pragma unroll
      for (int mt = 0; mt < 2; ++mt)
        #pragma unroll
        for (int q = 0; q < 4; ++q) cst[g][mt][q] = 0.0f;
    __syncthreads();   // also orders prev epilogue buf1-reads vs t=0 writes

    for (int t = 0; t < 11; ++t) {
      const int rb   = (t & 1) * HBUFB;
      const int xrb  = (t & 1) * XBUFB;
      const int wbuf = HBUFB - rb;
      float xvA = 0.0f, xvB = 0.0f;
      if (stg) { xvA = xsrcA[(t + 1) * 48]; xvB = xsrcB[(t + 1) * 48]; }

      f32x16 acc0 = {0.f, 0.f, 0.f, 0.f, 0.f, 0.f, 0.f, 0.f,
                     0.f, 0.f, 0.f, 0.f, 0.f, 0.f, 0.f, 0.f};
      f32x16 acc1 = acc0;
      GEMM_PAIR(0);                    // group A, both m-tiles
      UPD4_L(0, 0, acc0, 0);           // A mt0 updates free acc0
      acc0 = (f32x16){0.f, 0.f, 0.f, 0.f, 0.f, 0.f, 0.f, 0.f,
                      0.f, 0.f, 0.f, 0.f, 0.f, 0.f, 0.f, 0.f};
      GEMM_MT(AR, acc0, 0);            // group B mt0 refills acc0
      UPD4_L(0, 0, acc1, 1);           // A mt1 overlaps B's MFMA stream
      acc1 = (f32x16){0.f, 0.f, 0.f, 0.f, 0.f, 0.f, 0.f, 0.f,
                      0.f, 0.f, 0.f, 0.f, 0.f, 0.f, 0.f, 0.f};
      GEMM_MT(AR, acc1, 1);            // group B mt1
      UPD4_L(1, AR, acc0, 0);
      UPD4_L(1, AR, acc1, 1);

      if (stg) {
        *(f16*)(smem + (XBUFB - xrb) + xdst) = (f16)xvA;
        *(f16*)(smem + AR + (XBUFB - xrb) + xdst) = (f16)xvB;
      }
      __syncthreads();   // ONE barrier per double t-step
    }

    // ---- t = 11 epilogue: reads buf1, writes wz ----
    {
      const int rb  = HBUFB;
      const int xrb = XBUFB;
      f32x16 acc0 = {0.f, 0.f, 0.f, 0.f, 0.f, 0.f, 0.f, 0.f,
                     0.f, 0.f, 0.f, 0.f, 0.f, 0.f, 0.f, 0.f};
      f32x16 acc1 = acc0;
      GEMM_PAIR(0);
      UPD4_G(0, bgA, acc0, 0);
      acc0 = (f32x16){0.f, 0.f, 0.f, 0.f, 0.f, 0.f, 0.f, 0.f,
                      0.f, 0.f, 0.f, 0.f, 0.f, 0.f, 0.f, 0.f};
      GEMM_MT(AR, acc0, 0);
      UPD4_G(0, bgA, acc1, 1);
      acc1 = (f32x16){0.f, 0.f, 0.f, 0.f, 0.f, 0.f, 0.f, 0.f,
                      0.f, 0.f, 0.f, 0.f, 0.f, 0.f, 0.f, 0.f};
      GEMM_MT(AR, acc1, 1);
      UPD4_G(1, bgB, acc0, 0);
      UPD4_G(1, bgB, acc1, 1);

      {
        int b = tid >> 5, k2 = tid & 31;     // 8 samples x 32
        int smp = bgA + b;                   // bgB = bgA+4 -> contiguous
        float h0 = ghour[smp];
        float a = ghb2[k2];
        #pragma unroll
        for (int ii = 0; ii < 16; ++ii) {
          float u = fmaxf(h0 * ghw1[ii] + ghb1[ii], 0.0f);
          a += u * ghw2[ii * 32 + k2];
        }
        wz[(size_t)smp * 544 + 512 + k2] = (f16)a;
      }
    }
  }
#undef BFRAG
#undef XFRAG
#undef GEMM_PAIR
#undef GEMM_MT
#undef UPD4_L
#undef UPD4_G
}

// ======================= prep: weight transpose fp32->f16 =======================
extern "C" __global__ void hwq_prep(const float* __restrict__ gdw1,
                                    const float* __restrict__ gdw2,
                                    const float* __restrict__ gdw3,
                                    f16* __restrict__ w1t, f16* __restrict__ w2t,
                                    f16* __restrict__ w3t)
{
  int i0 = blockIdx.x * 256 + threadIdx.x;
  int stride = gridDim.x * 256;
  for (int idx = i0; idx < 139264; idx += stride) {
    int n = idx / 544, k = idx - n * 544;
    w1t[idx] = (f16)gdw1[k * 256 + n];
  }
  for (int idx = i0; idx < 32768; idx += stride) {
    int n = idx >> 8, k = idx & 255;
    w2t[idx] = (f16)gdw2[k * 128 + n];
  }
  for (int idx = i0; idx < 4096; idx += stride) {
    int n = idx >> 7, k = idx & 127;
    w3t[idx] = (n < 30) ? (f16)gdw3[k * 30 + n] : (f16)0.0f;
  }
}

// ======================= Kernel B: decoder MLP =======================
extern "C" __global__ __launch_bounds__(256, 2)
void hwq_dec(const f16* __restrict__ wz, const f16* __restrict__ w1t,
             const f16* __restrict__ w2t, const f16* __restrict__ w3t,
             const float* __restrict__ gdb1, const float* __restrict__ gdb2,
             const float* __restrict__ gdb3, float* __restrict__ gout)
{
  __shared__ __align__(16) char smem[55296];
  f16* a1 = (f16*)smem;               // [64][280]
  f16* a2 = (f16*)(smem + 35840);     // [64][152]
  const int tid = threadIdx.x;
  const int lane = tid & 63;
  const int wv = tid >> 6;
  const int lr = lane & 15;
  const int lk = lane >> 4;
  const int s0 = blockIdx.x << 6;

  f32x4 acc1[4][4];
  #pragma unroll
  for (int nt = 0; nt < 4; ++nt) {
    float bb = gdb1[wv * 64 + nt * 16 + lr];
    f32x4 bv = {bb, bb, bb, bb};
    #pragma unroll
    for (int mt = 0; mt < 4; ++mt) acc1[mt][nt] = bv;
  }
  for (int kt = 0; kt < 17; ++kt) {
    f16x8 af[4];
    #pragma unroll
    for (int mt = 0; mt < 4; ++mt)
      af[mt] = *(const f16x8*)(wz + (size_t)(s0 + mt * 16 + lr) * 544 + kt * 32 + lk * 8);
    #pragma unroll
    for (int nt = 0; nt < 4; ++nt) {
      f16x8 bf = *(const f16x8*)(w1t + (size_t)(wv * 64 + nt * 16 + lr) * 544 + kt * 32 + lk * 8);
      #pragma unroll
      for (int mt = 0; mt < 4; ++mt)
        acc1[mt][nt] = MFMA16(af[mt], bf, acc1[mt][nt]);
    }
  }
  #pragma unroll
  for (int mt = 0; mt < 4; ++mt)
    #pragma unroll
    for (int nt = 0; nt < 4; ++nt) {
      int n = wv * 64 + nt * 16 + lr;
      #pragma unroll
      for (int r = 0; r < 4; ++r)
        a1[(mt * 16 + lk * 4 + r) * 280 + n] = (f16)fmaxf(acc1[mt][nt][r], 0.0f);
    }
  __syncthreads();

  f32x4 acc2[4][2];
  #pragma unroll
  for (int nt = 0; nt < 2; ++nt) {
    float bb = gdb2[wv * 32 + nt * 16 + lr];
    f32x4 bv = {bb, bb, bb, bb};
    #pragma unroll
    for (int mt = 0; mt < 4; ++mt) acc2[mt][nt] = bv;
  }
  for (int kt = 0; kt < 8; ++kt) {
    f16x8 af[4];
    #pragma unroll
    for (int mt = 0; mt < 4; ++mt)
      af[mt] = *(const f16x8*)(a1 + (mt * 16 + lr) * 280 + kt * 32 + lk * 8);
    #pragma unroll
    for (int nt = 0; nt < 2; ++nt) {
      f16x8 bf = *(const f16x8*)(w2t + (size_t)(wv * 32 + nt * 16 + lr) * 256 + kt * 32 + lk * 8);
      #pragma unroll
      for (int mt = 0; mt < 4; ++mt)
        acc2[mt][nt] = MFMA16(af[mt], bf, acc2[mt][nt]);
    }
  }
  __syncthreads();
  #pragma unroll
  for (int mt = 0; mt < 4; ++mt)
    #pragma unroll
    for (int nt = 0; nt < 2; ++nt) {
      int n = wv * 32 + nt * 16 + lr;
      #pragma unroll
      for (int r = 0; r < 4; ++r)
        a2[(mt * 16 + lk * 4 + r) * 152 + n] = (f16)fmaxf(acc2[mt][nt][r], 0.0f);
    }
  __syncthreads();

  if (wv < 2) {
    int n = wv * 16 + lr;
    float bb = (n < 30) ? gdb3[n] : 0.0f;
    f32x4 acc3[4];
    #pragma unroll
    for (int mt = 0; mt < 4; ++mt) { f32x4 bv = {bb, bb, bb, bb}; acc3[mt] = bv; }
    #pragma unroll
    for (int kt = 0; kt < 4; ++kt) {
      f16x8 bf = *(const f16x8*)(w3t + n * 128 + kt * 32 + lk * 8);
      #pragma unroll
      for (int mt = 0; mt < 4; ++mt) {
        f16x8 af = *(const f16x8*)(a2 + (mt * 16 + lr) * 152 + kt * 32 + lk * 8);
        acc3[mt] = MFMA16(af, bf, acc3[mt]);
      }
    }
    if (n < 30) {
      #pragma unroll
      for (int mt = 0; mt < 4; ++mt)
        #pragma unroll
        for (int r = 0; r < 4; ++r)
          gout[(size_t)(s0 + mt * 16 + lk * 4 + r) * 30 + n] = sigm(acc3[mt][r]);
    }
  }
}

// ======================= Fallback: monolithic kernel (R1) =======================
typedef _Float16 f16x4m __attribute__((ext_vector_type(4)));
#define OFF_B 46080
#define SMEM_BYTES (46080 + 17408)

extern "C" __global__ __launch_bounds__(256, 1)
void hwq_fused_mono(const float* __restrict__ gx, const float* __restrict__ ghour,
               const float* __restrict__ gcw, const float* __restrict__ gcb,
               const float* __restrict__ ghw1, const float* __restrict__ ghb1,
               const float* __restrict__ ghw2, const float* __restrict__ ghb2,
               const float* __restrict__ gdw1, const float* __restrict__ gdb1,
               const float* __restrict__ gdw2, const float* __restrict__ gdb2,
               const float* __restrict__ gdw3, const float* __restrict__ gdb3,
               float* __restrict__ gout)
{
  __shared__ __align__(16) char smem[SMEM_BYTES];
  const int tid = threadIdx.x;
  const int lane = tid & 63;
  const int wv = tid >> 6;
  const int mg = wv & 1;
  const int ng = wv >> 1;
  const int lr = lane & 15;
  const int lk = lane >> 4;
  const int bg = blockIdx.x << 4;

  f16x8 Ah[9][4];
  {
    f16* wst = (f16*)(smem);
    #pragma unroll
    for (int c = 0; c < 2; ++c) {
      __syncthreads();
      for (int i = tid; i < 18432; i += 256) {
        int oc = i / 288, rem = i - oc * 288;
        wst[i] = (f16)gcw[(c * 64 + oc) * 315 + 27 + rem];
      }
      __syncthreads();
      #pragma unroll
      for (int g = 0; g < 2; ++g) {
        int ocl = g * 32 + mg * 16 + lr;
        #pragma unroll
        for (int tap = 0; tap < 9; ++tap) {
          f16x8 f;
          #pragma unroll
          for (int j = 0; j < 8; ++j)
            f[j] = wst[ocl * 288 + (lk * 8 + j) * 9 + tap];
          Ah[tap][c * 2 + g] = f;
        }
      }
    }
  }
  f16x8 Ax[4];
  {
    f16* xw = (f16*)(smem + OFF_B);
    __syncthreads();
    for (int i = tid; i < 3456; i += 256) {
      int oc = i / 27, rem = i - oc * 27;
      xw[i] = (f16)gcw[oc * 315 + rem];
    }
    __syncthreads();
    #pragma unroll
    for (int mt = 0; mt < 4; ++mt) {
      int oc = mt * 32 + mg * 16 + lr;
      f16x8 f;
      #pragma unroll
      for (int j = 0; j < 8; ++j) {
        int k = lk * 8 + j;
        int tap = (k * 11) >> 5;
        int ic = k - 3 * tap;
        f16 v = (f16)0.0f;
        if (k < 27) v = xw[oc * 27 + ic * 9 + tap];
        f[j] = v;
      }
      Ax[mt] = f;
    }
    __syncthreads();
  }

  float bias[4][4];
  #pragma unroll
  for (int mt = 0; mt < 4; ++mt)
    #pragma unroll
    for (int r = 0; r < 4; ++r)
      bias[mt][r] = gcb[mt * 32 + mg * 16 + lk * 4 + r];

  {
    float* za = (float*)smem;
    for (int i = tid; i < 11520; i += 256) za[i] = 0.0f;
    float* zb = (float*)(smem + OFF_B);
    for (int i = tid; i < 1152; i += 256) zb[i] = 0.0f;
    __syncthreads();
    for (int i = tid; i < 768; i += 256) {
      int b = i / 48, rem = i - b * 48;
      int pos = rem & 15;
      int ic = rem >> 4;
      int pp = (pos >> 2) * 6 + (pos & 3) + 7;
      *(f16*)(smem + OFF_B + b * 288 + pp * 8 + ic * 2) =
          (f16)gx[(size_t)(bg + b) * 576 + rem];
    }
    __syncthreads();
  }

  int hbase[8], xbase[8], wbase[8];
  #pragma unroll
  for (int nt = 0; nt < 8; ++nt) {
    int n = ng * 128 + nt * 16 + lr;
    int b = n >> 4, pos = n & 15;
    int pp0 = (pos >> 2) * 6 + (pos & 3);
    hbase[nt] = b * 2880 + pp0 * 80 + lk * 16;
    xbase[nt] = OFF_B + b * 288 + pp0 * 8;
    wbase[nt] = b * 2880 + (pp0 + 7) * 80 + (mg * 16 + lk * 4) * 2;
  }
  int xoff[8], xval[8];
  #pragma unroll
  for (int j = 0; j < 8; ++j) {
    int k = lk * 8 + j;
    int tap = (k * 11) >> 5;
    int ic = k - 3 * tap;
    xoff[j] = ((tap / 3) * 6 + (tap % 3)) * 8 + ic * 2;
    xval[j] = (k < 27);
  }

  const int TOFF[9] = {0, 1, 2, 6, 7, 8, 12, 13, 14};

  f32x4 cst[8];
  #pragma unroll
  for (int nt = 0; nt < 8; ++nt) { f32x4 z = {0.f, 0.f, 0.f, 0.f}; cst[nt] = z; }

  for (int t = 0; t < 12; ++t) {
    f32x4 acc[4][8];
    #pragma unroll
    for (int mt = 0; mt < 4; ++mt) {
      f32x4 bi = {bias[mt][0], bias[mt][1], bias[mt][2], bias[mt][3]};
      #pragma unroll
      for (int nt = 0; nt < 8; ++nt) acc[mt][nt] = bi;
    }
    #pragma unroll
    for (int tap = 0; tap < 9; ++tap) {
      #pragma unroll
      for (int nt = 0; nt < 8; ++nt) {
        f16x8 bf = *(const f16x8*)(smem + hbase[nt] + TOFF[tap] * 80);
        #pragma unroll
        for (int mt = 0; mt < 4; ++mt)
          acc[mt][nt] = MFMA16(Ah[tap][mt], bf, acc[mt][nt]);
      }
    }
    #pragma unroll
    for (int nt = 0; nt < 8; ++nt) {
      f16x8 bf;
      #pragma unroll
      for (int j = 0; j < 8; ++j) {
        int a = xval[j] ? (xbase[nt] + xoff[j]) : OFF_B;
        bf[j] = *(const f16*)(smem + a);
      }
      #pragma unroll
      for (int mt = 0; mt < 4; ++mt)
        acc[mt][nt] = MFMA16(Ax[mt], bf, acc[mt][nt]);
    }
    __syncthreads();

    #pragma unroll
    for (int nt = 0; nt < 8; ++nt) {
      f16 hh[4];
      #pragma unroll
      for (int r = 0; r < 4; ++r) {
        float ig = sigm(acc[0][nt][r]);
        float fg = sigm(acc[1][nt][r]);
        float og = sigm(acc[2][nt][r]);
        float gg = tanh_(acc[3][nt][r]);
        float cn = fg * cst[nt][r] + ig * gg;
        cst[nt][r] = cn;
        hh[r] = (f16)(og * tanh_(cn));
      }
      if (t < 11) {
        f16x4m hv = {hh[0], hh[1], hh[2], hh[3]};
        *(f16x4m*)(smem + wbase[nt]) = hv;
      } else {
        int n = ng * 128 + nt * 16 + lr;
        int b = n >> 4, pos = n & 15;
        int ch0 = mg * 16 + lk * 4;
        #pragma unroll
        for (int r = 0; r < 4; ++r)
          *(f16*)(smem + OFF_B + b * 1088 + (ch0 + r) * 32 + pos * 2) = hh[r];
      }
    }
    if (t < 11) {
      for (int i = tid; i < 768; i += 256) {
        int b = i / 48, rem = i - b * 48;
        int pos = rem & 15;
        int ic = rem >> 4;
        int pp = (pos >> 2) * 6 + (pos & 3) + 7;
        *(f16*)(smem + OFF_B + b * 288 + pp * 8 + ic * 2) =
            (f16)gx[(size_t)(bg + b) * 576 + (t + 1) * 48 + rem];
      }
    } else {
      for (int i = tid; i < 512; i += 256) {
        int b = i >> 5, k2 = i & 31;
        float h0 = ghour[bg + b];
        float a = ghb2[k2];
        #pragma unroll
        for (int ii = 0; ii < 16; ++ii) {
          float u = fmaxf(h0 * ghw1[ii] + ghb1[ii], 0.0f);
          a += u * ghw2[ii * 32 + k2];
        }
        *(f16*)(smem + OFF_B + b * 1088 + (512 + k2) * 2) = (f16)a;
      }
    }
    __syncthreads();
  }

  f16* zz  = (f16*)(smem + OFF_B);
  f16* wch = (f16*)(smem);
  f16* a1  = (f16*)(smem + 16384);
  f16* a2  = (f16*)(smem + 24576);
  f16* w3s = (f16*)(smem + 28672);

  f32x4 acc1[4];
  #pragma unroll
  for (int i = 0; i < 4; ++i) { f32x4 z = {0.f, 0.f, 0.f, 0.f}; acc1[i] = z; }
  for (int kt = 0; kt < 17; ++kt) {
    __syncthreads();
    for (int i = tid; i < 8192; i += 256) {
      int k = i >> 8, n = i & 255;
      wch[i] = (f16)gdw1[(kt * 32 + k) * 256 + n];
    }
    __syncthreads();
    f16x8 af = *(const f16x8*)((char*)zz + lr * 1088 + (kt * 32 + lk * 8) * 2);
    #pragma unroll
    for (int nt = 0; nt < 4; ++nt) {
      int n = (wv * 4 + nt) * 16 + lr;
      f16x8 bf;
      #pragma unroll
      for (int j = 0; j < 8; ++j) bf[j] = wch[(lk * 8 + j) * 256 + n];
      acc1[nt] = MFMA16(af, bf, acc1[nt]);
    }
  }
  __syncthreads();
  #pragma unroll
  for (int nt = 0; nt < 4; ++nt) {
    int n = (wv * 4 + nt) * 16 + lr;
    float bb = gdb1[n];
    #pragma unroll
    for (int r = 0; r < 4; ++r)
      a1[(lk * 4 + r) * 256 + n] = (f16)fmaxf(acc1[nt][r] + bb, 0.0f);
  }

  f32x4 acc2[2];
  #pragma unroll
  for (int i = 0; i < 2; ++i) { f32x4 z = {0.f, 0.f, 0.f, 0.f}; acc2[i] = z; }
  for (int kt = 0; kt < 8; ++kt) {
    __syncthreads();
    for (int i = tid; i < 4096; i += 256) {
      int k = i >> 7, n = i & 127;
      wch[i] = (f16)gdw2[(kt * 32 + k) * 128 + n];
    }
    __syncthreads();
    f16x8 af = *(const f16x8*)((char*)a1 + lr * 512 + (kt * 32 + lk * 8) * 2);
    #pragma unroll
    for (int nt = 0; nt < 2; ++nt) {
      int n = (wv * 2 + nt) * 16 + lr;
      f16x8 bf;
      #pragma unroll
      for (int j = 0; j < 8; ++j) bf[j] = wch[(lk * 8 + j) * 128 + n];
      acc2[nt] = MFMA16(af, bf, acc2[nt]);
    }
  }
  __syncthreads();
  #pragma unroll
  for (int nt = 0; nt < 2; ++nt) {
    int n = (wv * 2 + nt) * 16 + lr;
    float bb = gdb2[n];
    #pragma unroll
    for (int r = 0; r < 4; ++r)
      a2[(lk * 4 + r) * 128 + n] = (f16)fmaxf(acc2[nt][r] + bb, 0.0f);
  }
  __syncthreads();

  for (int i = tid; i < 4096; i += 256) {
    int k = i >> 5, n = i & 31;
    w3s[i] = (n < 30) ? (f16)gdw3[k * 30 + n] : (f16)0.0f;
  }
  __syncthreads();
  if (wv < 2) {
    f32x4 acc3 = {0.f, 0.f, 0.f, 0.f};
    int n = wv * 16 + lr;
    #pragma unroll
    for (int kt = 0; kt < 4; ++kt) {
      f16x8 af = *(const f16x8*)((char*)a2 + lr * 256 + (kt * 32 + lk * 8) * 2);
      f16x8 bf;
      #pragma unroll
      for (int j = 0; j < 8; ++j) bf[j] = w3s[(kt * 32 + lk * 8 + j) * 32 + n];
      acc3 = MFMA16(af, bf, acc3);
    }
    if (n < 30) {
      float bb = gdb3[n];
      #pragma unroll
      for (int r = 0; r < 4; ++r) {
        float v = sigm(acc3[r] + bb);
        gout[(size_t)(bg + lk * 4 + r) * 30 + n] = v;
      }
    }
  }
}

extern "C" void kernel_launch(void* const* d_in, const int* in_sizes, int n_in,
                              void* d_out, int out_size, void* d_ws, size_t ws_size,
                              hipStream_t stream) {
  (void)in_sizes; (void)n_in; (void)out_size;
  const size_t W1OFF = 35651584;             // z: 32768*544*2
  const size_t W2OFF = W1OFF + 278528;       // w1t
  const size_t W3OFF = W2OFF + 65536;        // w2t
  const size_t NEED  = W3OFF + 8192;         // w3t
  if (ws_size >= NEED) {
    f16* wzp = (f16*)d_ws;
    f16* w1t = (f16*)((char*)d_ws + W1OFF);
    f16* w2t = (f16*)((char*)d_ws + W2OFF);
    f16* w3t = (f16*)((char*)d_ws + W3OFF);
    hwq_prep<<<256, 256, 0, stream>>>((const float*)d_in[8], (const float*)d_in[10],
                                      (const float*)d_in[12], w1t, w2t, w3t);
    hwq_rec<<<GRID_REC, 256, 0, stream>>>(
        (const float*)d_in[0], (const float*)d_in[1], (const float*)d_in[2],
        (const float*)d_in[3], (const float*)d_in[4], (const float*)d_in[5],
        (const float*)d_in[6], (const float*)d_in[7], wzp);
    hwq_dec<<<512, 256, 0, stream>>>(wzp, w1t, w2t, w3t,
                                     (const float*)d_in[9], (const float*)d_in[11],
                                     (const float*)d_in[13], (float*)d_out);
  } else {
    hwq_fused_mono<<<2048, 256, 0, stream>>>(
        (const float*)d_in[0],  (const float*)d_in[1],  (const float*)d_in[2],
        (const float*)d_in[3],  (const float*)d_in[4],  (const float*)d_in[5],
        (const float*)d_in[6],  (const float*)d_in[7],  (const float*)d_in[8],
        (const float*)d_in[9],  (const float*)d_in[10], (const float*)d_in[11],
        (const float*)d_in[12], (const float*)d_in[13], (float*)d_out);
  }
}

// Round 10
// 633.037 us; speedup vs baseline: 2.3137x; 2.3137x over previous
//
#include <hip/hip_runtime.h>

typedef _Float16 f16;
typedef _Float16 f16x4 __attribute__((ext_vector_type(4)));
typedef _Float16 f16x8 __attribute__((ext_vector_type(8)));
typedef float f32x2 __attribute__((ext_vector_type(2)));
typedef float f32x4 __attribute__((ext_vector_type(4)));

#define MFMA16(a, b, c) __builtin_amdgcn_mfma_f32_16x16x32_f16((a), (b), (c), 0, 0, 0)

__device__ __forceinline__ float rcp_(float x) { return __builtin_amdgcn_rcpf(x); }
__device__ __forceinline__ float sigm(float v) { return rcp_(1.0f + __expf(-v)); }
__device__ __forceinline__ float tanh_(float v) { return 1.0f - 2.0f * rcp_(__expf(2.0f * v) + 1.0f); }
__device__ __forceinline__ float exp2_(float x) { return __builtin_amdgcn_exp2f(x); }

// ============ Kernel A: persistent ConvLSTM recurrence (all-register A) ========
// R16 = R13 (verified best: rec 584 us, total 638.4, Occ 32.7%, 3 blocks/CU)
// + T5 s_setprio(1) around MFMA segments. R13's regime matches T5's prereq:
// 3 independent blocks/CU at different phases -> a wave's MFMA run can preempt
// other blocks' LDS/staging. (R8/R9 lesson: 32x32 MFMA and 3-group variants
// both spill at the ~240-reg cliff -> this M=32xN=64 / 2-group structure is
// the register-feasible optimum; its LDS pipe measures ~84% busy.)
//
// Arena: hpad[2] [4 b][36 cell][80 B] 0..23040 (cell 80 B, sample 2880 B)
//        xpad[2] [4 b][36 cell][8 B]  23040..25344
#define LOG2E 1.4426950408889634f
#define HCELL 80
#define HSAMP 2880
#define HBUFB 11520
#define XP0 23040
#define XBUFB 1152
#define AR 25344
#define WSO 25344
#define SMEMA 50688
#define NPAIR 4096
#define GRID_REC 768

extern "C" __global__ __launch_bounds__(256, 3)
void hwq_rec(const float* __restrict__ gx, const float* __restrict__ ghour,
             const float* __restrict__ gcw, const float* __restrict__ gcb,
             const float* __restrict__ ghw1, const float* __restrict__ ghb1,
             const float* __restrict__ ghw2, const float* __restrict__ ghb2,
             f16* __restrict__ wz)
{
  __shared__ __align__(16) char smem[SMEMA];
  const int tid = threadIdx.x;
  const int lane = tid & 63;
  const int wv = tid >> 6;              // M-chunk: rows [wv*32, wv*32+32)
  const int lr = lane & 15;
  const int lk = lane >> 4;
  const int TOFF[9] = {0, 1, 2, 6, 7, 8, 12, 13, 14};
  const int pp0 = (lr >> 2) * 6 + (lr & 3);

  // ---- prologue 1 (WS = arena B space, used BEFORE arenas are zeroed):
  //      stage scaled Ax1 table [128 m][32 k]; gather Ax1; Ax2 direct ----
  f16x8 Ax1[2], Ax2[2];
  {
    f16* axs = (f16*)(smem + WSO);
    for (int i = tid; i < 4096; i += 256) {
      int m = i >> 5, k = i & 31;
      int tau = k >> 2, sl = k & 3;
      int oc = ((m & 3) << 5) + (m >> 2);
      float sc = ((m & 3) == 3) ? (2.0f * LOG2E) : (-LOG2E);
      f16 v = (f16)0.0f;
      if (sl < 3) v = (f16)(sc * gcw[oc * 315 + sl * 9 + tau]);
      else if (tau == 4) v = (f16)(sc * gcb[oc]);
      axs[i] = v;
    }
    __syncthreads();
    #pragma unroll
    for (int mt = 0; mt < 2; ++mt) {
      Ax1[mt] = *(const f16x8*)(smem + WSO + (wv * 32 + mt * 16 + lr) * 64 + lk * 16);
      int m = wv * 32 + mt * 16 + lr;
      int oc = ((m & 3) << 5) + (m >> 2);
      float sc = ((m & 3) == 3) ? (2.0f * LOG2E) : (-LOG2E);
      f16x8 f = {(f16)0, (f16)0, (f16)0, (f16)0, (f16)0, (f16)0, (f16)0, (f16)0};
      if (lk == 0) {
        f[0] = (f16)(sc * gcw[oc * 315 + 8]);
        f[1] = (f16)(sc * gcw[oc * 315 + 17]);
        f[2] = (f16)(sc * gcw[oc * 315 + 26]);
      }
      Ax2[mt] = f;
    }
    __syncthreads();
  }
  // ---- prologue 2: 9 tap A-frags for this wave's 32 rows via 4 staged chunks
  f16x8 Ah[9][2];
  {
    f16* wst = (f16*)(smem + WSO);   // [32 row][288 = ch*9+tap]
    #pragma unroll
    for (int c = 0; c < 4; ++c) {
      for (int i = tid; i < 9216; i += 256) {
        int mrow = i / 288, rem = i - mrow * 288;
        int m = c * 32 + mrow;
        int oc = ((m & 3) << 5) + (m >> 2);
        float sc = ((m & 3) == 3) ? (2.0f * LOG2E) : (-LOG2E);
        wst[i] = (f16)(sc * gcw[oc * 315 + 27 + rem]);
      }
      __syncthreads();
      if (wv == c) {
        #pragma unroll
        for (int mt = 0; mt < 2; ++mt) {
          #pragma unroll
          for (int tap = 0; tap < 9; ++tap) {
            f16x8 f;
            #pragma unroll
            for (int j = 0; j < 8; ++j)
              f[j] = wst[(mt * 16 + lr) * 288 + (lk * 8 + j) * 9 + tap];
            Ah[tap][mt] = f;
          }
        }
      }
      __syncthreads();
    }
  }
  // ---- prologue 3: zero BOTH arenas (over WS); bias flags in all 4 xpads ----
  {
    float* za = (float*)smem;
    for (int i = tid; i < 12672; i += 256) za[i] = 0.0f;   // 50688 B
    __syncthreads();
    {
      int ar = tid >> 7, xb = (tid >> 6) & 1, b = (tid >> 4) & 3, p = tid & 15;
      int cell = ((p >> 2) + 1) * 6 + (p & 3) + 1;
      *(f16*)(smem + ar * AR + XP0 + xb * XBUFB + b * 288 + cell * 8 + 6) = (f16)1.0f;
    }
    __syncthreads();
  }

  // ---- hot-loop bases (arena-relative, pair-invariant) ----
  const int hb  = pp0 * HCELL + lk * 16;                     // + nt*HSAMP
  const int xpb = XP0 + pp0 * 8;                             // + nt*288
  const int wb  = (pp0 + 7) * HCELL + (wv * 8 + lk) * 2;     // + nt*HSAMP + mt*8
  const int xo0 = TOFF[2 * lk] * 8;
  const int xo1 = TOFF[2 * lk + 1] * 8;
  const bool stg = tid < 192;
  const int sb = tid / 48, srem = tid - sb * 48;
  const int sp = srem & 15, sic = srem >> 4;
  const int xdst = XP0 + sb * 288 + (((sp >> 2) + 1) * 6 + (sp & 3) + 1) * 8 + sic * 2;
  const int zb_ = tid >> 6, zc16 = (tid >> 2) & 15, zpart = tid & 3;
  const int zaddr = zb_ * HSAMP + ((zc16 >> 2) * 6 + (zc16 & 3) + 7) * HCELL + zpart * 16;

  const f32x4 Z0v = {0.f, 0.f, 0.f, 0.f};

// x+bias MFMAs, chain start (C = zero quad); ab = arena byte offset
#define XPH(ab, nt) { \
    const int base_ = (ab) + xrb + xpb + (nt) * 288; \
    f16x4 lo_ = *(const f16x4*)(smem + base_ + xo0); \
    f16x4 hi_ = *(const f16x4*)(smem + base_ + xo1); \
    f16x8 bf1_ = __builtin_shufflevector(lo_, hi_, 0, 1, 2, 3, 4, 5, 6, 7); \
    f16x4 l8_ = *(const f16x4*)(smem + base_ + 112); \
    f16x8 bf2_ = __builtin_shufflevector(l8_, l8_, 0, 1, 2, 3, 0, 1, 2, 3); \
    _Pragma("unroll") for (int mt = 0; mt < 2; ++mt) { \
      acc[mt][nt] = MFMA16(Ax1[mt], bf1_, Z0v); \
      acc[mt][nt] = MFMA16(Ax2[mt], bf2_, acc[mt][nt]); } }

// all 9 tap-GEMMs for one nt
#define TAPS(ab, nt) \
    _Pragma("unroll") for (int tap = 0; tap < 9; ++tap) { \
      f16x8 bf_ = *(const f16x8*)(smem + (ab) + rb + hb + (nt) * HSAMP + TOFF[tap] * HCELL); \
      _Pragma("unroll") for (int mt = 0; mt < 2; ++mt) \
        acc[mt][nt] = MFMA16(Ah[tap][mt], bf_, acc[mt][nt]); }

#define PRIO1 __builtin_amdgcn_s_setprio(1)
#define PRIO0 __builtin_amdgcn_s_setprio(0)

// cell update, h -> LDS (other buffer). acc pre-scaled: (i,f,o)*-log2e, g*2log2e.
#define UPD_L(g, ab, mt, nt) { \
    float Ei = exp2_(acc[mt][nt][0]); \
    float Ef = exp2_(acc[mt][nt][1]); \
    float Eo = exp2_(acc[mt][nt][2]); \
    float Eg = exp2_(acc[mt][nt][3]); \
    float fg = rcp_(1.0f + Ef); \
    float pq = rcp_((1.0f + Ei) * (1.0f + Eg)); \
    float cn = fmaf(fg, cst[g][mt][nt], (2.0f * LOG2E) * ((Eg - 1.0f) * pq)); \
    cst[g][mt][nt] = cn; \
    float Ec = exp2_(cn); \
    *(f16*)(smem + (ab) + wbuf + wb + (nt) * HSAMP + (mt) * 8) = \
        (f16)((Ec - 1.0f) * rcp_((1.0f + Eo) * (1.0f + Ec))); }

// cell update, h -> global wz (t = 11)
#define UPD_G(g, bgv, mt, nt) { \
    float Ei = exp2_(acc[mt][nt][0]); \
    float Ef = exp2_(acc[mt][nt][1]); \
    float Eo = exp2_(acc[mt][nt][2]); \
    float Eg = exp2_(acc[mt][nt][3]); \
    float fg = rcp_(1.0f + Ef); \
    float pq = rcp_((1.0f + Ei) * (1.0f + Eg)); \
    float cn = fmaf(fg, cst[g][mt][nt], (2.0f * LOG2E) * ((Eg - 1.0f) * pq)); \
    float Ec = exp2_(cn); \
    wz[(size_t)((bgv) + (nt)) * 544 + (wv * 8 + (mt) * 4 + lk) * 16 + lr] = \
        (f16)((Ec - 1.0f) * rcp_((1.0f + Eo) * (1.0f + Ec))); }

  // balanced contiguous partition: 4096 = 768*5 + 256
  const int bid = blockIdx.x;
  const int q_ = NPAIR / GRID_REC;                    // 5
  const int r_ = NPAIR - q_ * GRID_REC;               // 256
  const int myn = q_ + (bid < r_ ? 1 : 0);
  const int mys = (bid < r_) ? bid * (q_ + 1) : r_ * (q_ + 1) + (bid - r_) * q_;

  for (int pi = 0; pi < myn; ++pi) {
    const int pr = mys + pi;
    const int bgA = pr << 3;          // samples bgA..bgA+3
    const int bgB = bgA + 4;          // samples bgB..bgB+3
    const float* xsrcA = gx + (size_t)(bgA + sb) * 576 + srem;
    const float* xsrcB = gx + (size_t)(bgB + sb) * 576 + srem;

    // pair re-init: zero buf0 interiors (h0 = 0), stage xpad0(t=0), cst = 0
    {
      f32x2 z2 = {0.f, 0.f};
      *(f32x2*)(smem + zaddr) = z2;
      *(f32x2*)(smem + zaddr + 8) = z2;
      *(f32x2*)(smem + AR + zaddr) = z2;
      *(f32x2*)(smem + AR + zaddr + 8) = z2;
    }
    if (stg) {
      *(f16*)(smem + xdst) = (f16)xsrcA[0];
      *(f16*)(smem + AR + xdst) = (f16)xsrcB[0];
    }
    float cst[2][2][4];
    #pragma unroll
    for (int g = 0; g < 2; ++g)
      #pragma unroll
      for (int mt = 0; mt < 2; ++mt)
        #pragma unroll
        for (int nt = 0; nt < 4; ++nt) cst[g][mt][nt] = 0.0f;
    __syncthreads();   // also orders prev epilogue buf1-reads vs t=0 buf1-writes

    for (int t = 0; t < 11; ++t) {
      const int rb   = (t & 1) * HBUFB;      // read buffer
      const int xrb  = (t & 1) * XBUFB;
      const int wbuf = HBUFB - rb;
      float xvA = 0.0f, xvB = 0.0f;
      if (stg) { xvA = xsrcA[(t + 1) * 48]; xvB = xsrcB[(t + 1) * 48]; }

      f32x4 acc[2][4];
      // ---- group A: full MFMA phase (4 nt chains) ----
      PRIO1;
      XPH(0, 0); TAPS(0, 0);
      XPH(0, 1); TAPS(0, 1);
      XPH(0, 2); TAPS(0, 2);
      XPH(0, 3); TAPS(0, 3);
      PRIO0;
      // A updates interleave with B's refill of the freed acc quads
      UPD_L(0, 0, 0, 0); UPD_L(0, 0, 1, 0);
      PRIO1; XPH(AR, 0); TAPS(AR, 0); PRIO0;
      UPD_L(0, 0, 0, 1); UPD_L(0, 0, 1, 1);
      PRIO1; XPH(AR, 1); TAPS(AR, 1); PRIO0;
      UPD_L(0, 0, 0, 2); UPD_L(0, 0, 1, 2);
      PRIO1; XPH(AR, 2); TAPS(AR, 2); PRIO0;
      UPD_L(0, 0, 0, 3); UPD_L(0, 0, 1, 3);
      PRIO1; XPH(AR, 3); TAPS(AR, 3); PRIO0;
      UPD_L(1, AR, 0, 0); UPD_L(1, AR, 1, 0);
      UPD_L(1, AR, 0, 1); UPD_L(1, AR, 1, 1);
      UPD_L(1, AR, 0, 2); UPD_L(1, AR, 1, 2);
      UPD_L(1, AR, 0, 3); UPD_L(1, AR, 1, 3);

      if (stg) {
        *(f16*)(smem + (XBUFB - xrb) + xdst) = (f16)xvA;
        *(f16*)(smem + AR + (XBUFB - xrb) + xdst) = (f16)xvB;
      }
      __syncthreads();   // ONE barrier per double t-step
    }

    // ---- t = 11 epilogue: reads buf1, writes wz; no trailing barrier needed
    {
      const int rb  = HBUFB;
      const int xrb = XBUFB;
      f32x4 acc[2][4];
      PRIO1;
      XPH(0, 0); TAPS(0, 0);
      XPH(0, 1); TAPS(0, 1);
      XPH(0, 2); TAPS(0, 2);
      XPH(0, 3); TAPS(0, 3);
      PRIO0;
      UPD_G(0, bgA, 0, 0); UPD_G(0, bgA, 1, 0);
      PRIO1; XPH(AR, 0); TAPS(AR, 0); PRIO0;
      UPD_G(0, bgA, 0, 1); UPD_G(0, bgA, 1, 1);
      PRIO1; XPH(AR, 1); TAPS(AR, 1); PRIO0;
      UPD_G(0, bgA, 0, 2); UPD_G(0, bgA, 1, 2);
      PRIO1; XPH(AR, 2); TAPS(AR, 2); PRIO0;
      UPD_G(0, bgA, 0, 3); UPD_G(0, bgA, 1, 3);
      PRIO1; XPH(AR, 3); TAPS(AR, 3); PRIO0;
      UPD_G(1, bgB, 0, 0); UPD_G(1, bgB, 1, 0);
      UPD_G(1, bgB, 0, 1); UPD_G(1, bgB, 1, 1);
      UPD_G(1, bgB, 0, 2); UPD_G(1, bgB, 1, 2);
      UPD_G(1, bgB, 0, 3); UPD_G(1, bgB, 1, 3);

      {
        int b = tid >> 5, k2 = tid & 31;     // b in 0..7 -> 8 samples
        int smp = bgA + b;                   // bgB = bgA+4 -> contiguous
        float h0 = ghour[smp];
        float a = ghb2[k2];
        #pragma unroll
        for (int ii = 0; ii < 16; ++ii) {
          float u = fmaxf(h0 * ghw1[ii] + ghb1[ii], 0.0f);
          a += u * ghw2[ii * 32 + k2];
        }
        wz[(size_t)smp * 544 + 512 + k2] = (f16)a;
      }
    }
  }
#undef XPH
#undef TAPS
#undef UPD_L
#undef UPD_G
#undef PRIO1
#undef PRIO0
}

// ======================= prep: weight transpose fp32->f16 =======================
extern "C" __global__ void hwq_prep(const float* __restrict__ gdw1,
                                    const float* __restrict__ gdw2,
                                    const float* __restrict__ gdw3,
                                    f16* __restrict__ w1t, f16* __restrict__ w2t,
                                    f16* __restrict__ w3t)
{
  int i0 = blockIdx.x * 256 + threadIdx.x;
  int stride = gridDim.x * 256;
  for (int idx = i0; idx < 139264; idx += stride) {
    int n = idx / 544, k = idx - n * 544;
    w1t[idx] = (f16)gdw1[k * 256 + n];
  }
  for (int idx = i0; idx < 32768; idx += stride) {
    int n = idx >> 8, k = idx & 255;
    w2t[idx] = (f16)gdw2[k * 128 + n];
  }
  for (int idx = i0; idx < 4096; idx += stride) {
    int n = idx >> 7, k = idx & 127;
    w3t[idx] = (n < 30) ? (f16)gdw3[k * 30 + n] : (f16)0.0f;
  }
}

// ======================= Kernel B: decoder MLP =======================
extern "C" __global__ __launch_bounds__(256, 2)
void hwq_dec(const f16* __restrict__ wz, const f16* __restrict__ w1t,
             const f16* __restrict__ w2t, const f16* __restrict__ w3t,
             const float* __restrict__ gdb1, const float* __restrict__ gdb2,
             const float* __restrict__ gdb3, float* __restrict__ gout)
{
  __shared__ __align__(16) char smem[55296];
  f16* a1 = (f16*)smem;               // [64][280]
  f16* a2 = (f16*)(smem + 35840);     // [64][152]
  const int tid = threadIdx.x;
  const int lane = tid & 63;
  const int wv = tid >> 6;
  const int lr = lane & 15;
  const int lk = lane >> 4;
  const int s0 = blockIdx.x << 6;

  f32x4 acc1[4][4];
  #pragma unroll
  for (int nt = 0; nt < 4; ++nt) {
    float bb = gdb1[wv * 64 + nt * 16 + lr];
    f32x4 bv = {bb, bb, bb, bb};
    #pragma unroll
    for (int mt = 0; mt < 4; ++mt) acc1[mt][nt] = bv;
  }
  for (int kt = 0; kt < 17; ++kt) {
    f16x8 af[4];
    #pragma unroll
    for (int mt = 0; mt < 4; ++mt)
      af[mt] = *(const f16x8*)(wz + (size_t)(s0 + mt * 16 + lr) * 544 + kt * 32 + lk * 8);
    #pragma unroll
    for (int nt = 0; nt < 4; ++nt) {
      f16x8 bf = *(const f16x8*)(w1t + (size_t)(wv * 64 + nt * 16 + lr) * 544 + kt * 32 + lk * 8);
      #pragma unroll
      for (int mt = 0; mt < 4; ++mt)
        acc1[mt][nt] = MFMA16(af[mt], bf, acc1[mt][nt]);
    }
  }
  #pragma unroll
  for (int mt = 0; mt < 4; ++mt)
    #pragma unroll
    for (int nt = 0; nt < 4; ++nt) {
      int n = wv * 64 + nt * 16 + lr;
      #pragma unroll
      for (int r = 0; r < 4; ++r)
        a1[(mt * 16 + lk * 4 + r) * 280 + n] = (f16)fmaxf(acc1[mt][nt][r], 0.0f);
    }
  __syncthreads();

  f32x4 acc2[4][2];
  #pragma unroll
  for (int nt = 0; nt < 2; ++nt) {
    float bb = gdb2[wv * 32 + nt * 16 + lr];
    f32x4 bv = {bb, bb, bb, bb};
    #pragma unroll
    for (int mt = 0; mt < 4; ++mt) acc2[mt][nt] = bv;
  }
  for (int kt = 0; kt < 8; ++kt) {
    f16x8 af[4];
    #pragma unroll
    for (int mt = 0; mt < 4; ++mt)
      af[mt] = *(const f16x8*)(a1 + (mt * 16 + lr) * 280 + kt * 32 + lk * 8);
    #pragma unroll
    for (int nt = 0; nt < 2; ++nt) {
      f16x8 bf = *(const f16x8*)(w2t + (size_t)(wv * 32 + nt * 16 + lr) * 256 + kt * 32 + lk * 8);
      #pragma unroll
      for (int mt = 0; mt < 4; ++mt)
        acc2[mt][nt] = MFMA16(af[mt], bf, acc2[mt][nt]);
    }
  }
  __syncthreads();
  #pragma unroll
  for (int mt = 0; mt < 4; ++mt)
    #pragma unroll
    for (int nt = 0; nt < 2; ++nt) {
      int n = wv * 32 + nt * 16 + lr;
      #pragma unroll
      for (int r = 0; r < 4; ++r)
        a2[(mt * 16 + lk * 4 + r) * 152 + n] = (f16)fmaxf(acc2[mt][nt][r], 0.0f);
    }
  __syncthreads();

  if (wv < 2) {
    int n = wv * 16 + lr;
    float bb = (n < 30) ? gdb3[n] : 0.0f;
    f32x4 acc3[4];
    #pragma unroll
    for (int mt = 0; mt < 4; ++mt) { f32x4 bv = {bb, bb, bb, bb}; acc3[mt] = bv; }
    #pragma unroll
    for (int kt = 0; kt < 4; ++kt) {
      f16x8 bf = *(const f16x8*)(w3t + n * 128 + kt * 32 + lk * 8);
      #pragma unroll
      for (int mt = 0; mt < 4; ++mt) {
        f16x8 af = *(const f16x8*)(a2 + (mt * 16 + lr) * 152 + kt * 32 + lk * 8);
        acc3[mt] = MFMA16(af, bf, acc3[mt]);
      }
    }
    if (n < 30) {
      #pragma unroll
      for (int mt = 0; mt < 4; ++mt)
        #pragma unroll
        for (int r = 0; r < 4; ++r)
          gout[(size_t)(s0 + mt * 16 + lk * 4 + r) * 30 + n] = sigm(acc3[mt][r]);
    }
  }
}

// ======================= Fallback: monolithic kernel (R1) =======================
typedef _Float16 f16x4m __attribute__((ext_vector_type(4)));
#define OFF_B 46080
#define SMEM_BYTES (46080 + 17408)

extern "C" __global__ __launch_bounds__(256, 1)
void hwq_fused_mono(const float* __restrict__ gx, const float* __restrict__ ghour,
               const float* __restrict__ gcw, const float* __restrict__ gcb,
               const float* __restrict__ ghw1, const float* __restrict__ ghb1,
               const float* __restrict__ ghw2, const float* __restrict__ ghb2,
               const float* __restrict__ gdw1, const float* __restrict__ gdb1,
               const float* __restrict__ gdw2, const float* __restrict__ gdb2,
               const float* __restrict__ gdw3, const float* __restrict__ gdb3,
               float* __restrict__ gout)
{
  __shared__ __align__(16) char smem[SMEM_BYTES];
  const int tid = threadIdx.x;
  const int lane = tid & 63;
  const int wv = tid >> 6;
  const int mg = wv & 1;
  const int ng = wv >> 1;
  const int lr = lane & 15;
  const int lk = lane >> 4;
  const int bg = blockIdx.x << 4;

  f16x8 Ah[9][4];
  {
    f16* wst = (f16*)(smem);
    #pragma unroll
    for (int c = 0; c < 2; ++c) {
      __syncthreads();
      for (int i = tid; i < 18432; i += 256) {
        int oc = i / 288, rem = i - oc * 288;
        wst[i] = (f16)gcw[(c * 64 + oc) * 315 + 27 + rem];
      }
      __syncthreads();
      #pragma unroll
      for (int g = 0; g < 2; ++g) {
        int ocl = g * 32 + mg * 16 + lr;
        #pragma unroll
        for (int tap = 0; tap < 9; ++tap) {
          f16x8 f;
          #pragma unroll
          for (int j = 0; j < 8; ++j)
            f[j] = wst[ocl * 288 + (lk * 8 + j) * 9 + tap];
          Ah[tap][c * 2 + g] = f;
        }
      }
    }
  }
  f16x8 Ax[4];
  {
    f16* xw = (f16*)(smem + OFF_B);
    __syncthreads();
    for (int i = tid; i < 3456; i += 256) {
      int oc = i / 27, rem = i - oc * 27;
      xw[i] = (f16)gcw[oc * 315 + rem];
    }
    __syncthreads();
    #pragma unroll
    for (int mt = 0; mt < 4; ++mt) {
      int oc = mt * 32 + mg * 16 + lr;
      f16x8 f;
      #pragma unroll
      for (int j = 0; j < 8; ++j) {
        int k = lk * 8 + j;
        int tap = (k * 11) >> 5;
        int ic = k - 3 * tap;
        f16 v = (f16)0.0f;
        if (k < 27) v = xw[oc * 27 + ic * 9 + tap];
        f[j] = v;
      }
      Ax[mt] = f;
    }
    __syncthreads();
  }

  float bias[4][4];
  #pragma unroll
  for (int mt = 0; mt < 4; ++mt)
    #pragma unroll
    for (int r = 0; r < 4; ++r)
      bias[mt][r] = gcb[mt * 32 + mg * 16 + lk * 4 + r];

  {
    float* za = (float*)smem;
    for (int i = tid; i < 11520; i += 256) za[i] = 0.0f;
    float* zb = (float*)(smem + OFF_B);
    for (int i = tid; i < 1152; i += 256) zb[i] = 0.0f;
    __syncthreads();
    for (int i = tid; i < 768; i += 256) {
      int b = i / 48, rem = i - b * 48;
      int pos = rem & 15;
      int ic = rem >> 4;
      int pp = (pos >> 2) * 6 + (pos & 3) + 7;
      *(f16*)(smem + OFF_B + b * 288 + pp * 8 + ic * 2) =
          (f16)gx[(size_t)(bg + b) * 576 + rem];
    }
    __syncthreads();
  }

  int hbase[8], xbase[8], wbase[8];
  #pragma unroll
  for (int nt = 0; nt < 8; ++nt) {
    int n = ng * 128 + nt * 16 + lr;
    int b = n >> 4, pos = n & 15;
    int pp0 = (pos >> 2) * 6 + (pos & 3);
    hbase[nt] = b * 2880 + pp0 * 80 + lk * 16;
    xbase[nt] = OFF_B + b * 288 + pp0 * 8;
    wbase[nt] = b * 2880 + (pp0 + 7) * 80 + (mg * 16 + lk * 4) * 2;
  }
  int xoff[8], xval[8];
  #pragma unroll
  for (int j = 0; j < 8; ++j) {
    int k = lk * 8 + j;
    int tap = (k * 11) >> 5;
    int ic = k - 3 * tap;
    xoff[j] = ((tap / 3) * 6 + (tap % 3)) * 8 + ic * 2;
    xval[j] = (k < 27);
  }

  const int TOFF[9] = {0, 1, 2, 6, 7, 8, 12, 13, 14};

  f32x4 cst[8];
  #pragma unroll
  for (int nt = 0; nt < 8; ++nt) { f32x4 z = {0.f, 0.f, 0.f, 0.f}; cst[nt] = z; }

  for (int t = 0; t < 12; ++t) {
    f32x4 acc[4][8];
    #pragma unroll
    for (int mt = 0; mt < 4; ++mt) {
      f32x4 bi = {bias[mt][0], bias[mt][1], bias[mt][2], bias[mt][3]};
      #pragma unroll
      for (int nt = 0; nt < 8; ++nt) acc[mt][nt] = bi;
    }
    #pragma unroll
    for (int tap = 0; tap < 9; ++tap) {
      #pragma unroll
      for (int nt = 0; nt < 8; ++nt) {
        f16x8 bf = *(const f16x8*)(smem + hbase[nt] + TOFF[tap] * 80);
        #pragma unroll
        for (int mt = 0; mt < 4; ++mt)
          acc[mt][nt] = MFMA16(Ah[tap][mt], bf, acc[mt][nt]);
      }
    }
    #pragma unroll
    for (int nt = 0; nt < 8; ++nt) {
      f16x8 bf;
      #pragma unroll
      for (int j = 0; j < 8; ++j) {
        int a = xval[j] ? (xbase[nt] + xoff[j]) : OFF_B;
        bf[j] = *(const f16*)(smem + a);
      }
      #pragma unroll
      for (int mt = 0; mt < 4; ++mt)
        acc[mt][nt] = MFMA16(Ax[mt], bf, acc[mt][nt]);
    }
    __syncthreads();

    #pragma unroll
    for (int nt = 0; nt < 8; ++nt) {
      f16 hh[4];
      #pragma unroll
      for (int r = 0; r < 4; ++r) {
        float ig = sigm(acc[0][nt][r]);
        float fg = sigm(acc[1][nt][r]);
        float og = sigm(acc[2][nt][r]);
        float gg = tanh_(acc[3][nt][r]);
        float cn = fg * cst[nt][r] + ig * gg;
        cst[nt][r] = cn;
        hh[r] = (f16)(og * tanh_(cn));
      }
      if (t < 11) {
        f16x4m hv = {hh[0], hh[1], hh[2], hh[3]};
        *(f16x4m*)(smem + wbase[nt]) = hv;
      } else {
        int n = ng * 128 + nt * 16 + lr;
        int b = n >> 4, pos = n & 15;
        int ch0 = mg * 16 + lk * 4;
        #pragma unroll
        for (int r = 0; r < 4; ++r)
          *(f16*)(smem + OFF_B + b * 1088 + (ch0 + r) * 32 + pos * 2) = hh[r];
      }
    }
    if (t < 11) {
      for (int i = tid; i < 768; i += 256) {
        int b = i / 48, rem = i - b * 48;
        int pos = rem & 15;
        int ic = rem >> 4;
        int pp = (pos >> 2) * 6 + (pos & 3) + 7;
        *(f16*)(smem + OFF_B + b * 288 + pp * 8 + ic * 2) =
            (f16)gx[(size_t)(bg + b) * 576 + (t + 1) * 48 + rem];
      }
    } else {
      for (int i = tid; i < 512; i += 256) {
        int b = i >> 5, k2 = i & 31;
        float h0 = ghour[bg + b];
        float a = ghb2[k2];
        #pragma unroll
        for (int ii = 0; ii < 16; ++ii) {
          float u = fmaxf(h0 * ghw1[ii] + ghb1[ii], 0.0f);
          a += u * ghw2[ii * 32 + k2];
        }
        *(f16*)(smem + OFF_B + b * 1088 + (512 + k2) * 2) = (f16)a;
      }
    }
    __syncthreads();
  }

  f16* zz  = (f16*)(smem + OFF_B);
  f16* wch = (f16*)(smem);
  f16* a1  = (f16*)(smem + 16384);
  f16* a2  = (f16*)(smem + 24576);
  f16* w3s = (f16*)(smem + 28672);

  f32x4 acc1[4];
  #pragma unroll
  for (int i = 0; i < 4; ++i) { f32x4 z = {0.f, 0.f, 0.f, 0.f}; acc1[i] = z; }
  for (int kt = 0; kt < 17; ++kt) {
    __syncthreads();
    for (int i = tid; i < 8192; i += 256) {
      int k = i >> 8, n = i & 255;
      wch[i] = (f16)gdw1[(kt * 32 + k) * 256 + n];
    }
    __syncthreads();
    f16x8 af = *(const f16x8*)((char*)zz + lr * 1088 + (kt * 32 + lk * 8) * 2);
    #pragma unroll
    for (int nt = 0; nt < 4; ++nt) {
      int n = (wv * 4 + nt) * 16 + lr;
      f16x8 bf;
      #pragma unroll
      for (int j = 0; j < 8; ++j) bf[j] = wch[(lk * 8 + j) * 256 + n];
      acc1[nt] = MFMA16(af, bf, acc1[nt]);
    }
  }
  __syncthreads();
  #pragma unroll
  for (int nt = 0; nt < 4; ++nt) {
    int n = (wv * 4 + nt) * 16 + lr;
    float bb = gdb1[n];
    #pragma unroll
    for (int r = 0; r < 4; ++r)
      a1[(lk * 4 + r) * 256 + n] = (f16)fmaxf(acc1[nt][r] + bb, 0.0f);
  }

  f32x4 acc2[2];
  #pragma unroll
  for (int i = 0; i < 2; ++i) { f32x4 z = {0.f, 0.f, 0.f, 0.f}; acc2[i] = z; }
  for (int kt = 0; kt < 8; ++kt) {
    __syncthreads();
    for (int i = tid; i < 4096; i += 256) {
      int k = i >> 7, n = i & 127;
      wch[i] = (f16)gdw2[(kt * 32 + k) * 128 + n];
    }
    __syncthreads();
    f16x8 af = *(const f16x8*)((char*)a1 + lr * 512 + (kt * 32 + lk * 8) * 2);
    #pragma unroll
    for (int nt = 0; nt < 2; ++nt) {
      int n = (wv * 2 + nt) * 16 + lr;
      f16x8 bf;
      #pragma unroll
      for (int j = 0; j < 8; ++j) bf[j] = wch[(lk * 8 + j) * 128 + n];
      acc2[nt] = MFMA16(af, bf, acc2[nt]);
    }
  }
  __syncthreads();
  #pragma unroll
  for (int nt = 0; nt < 2; ++nt) {
    int n = (wv * 2 + nt) * 16 + lr;
    float bb = gdb2[n];
    #pragma unroll
    for (int r = 0; r < 4; ++r)
      a2[(lk * 4 + r) * 128 + n] = (f16)fmaxf(acc2[nt][r] + bb, 0.0f);
  }
  __syncthreads();

  for (int i = tid; i < 4096; i += 256) {
    int k = i >> 5, n = i & 31;
    w3s[i] = (n < 30) ? (f16)gdw3[k * 30 + n] : (f16)0.0f;
  }
  __syncthreads();
  if (wv < 2) {
    f32x4 acc3 = {0.f, 0.f, 0.f, 0.f};
    int n = wv * 16 + lr;
    #pragma unroll
    for (int kt = 0; kt < 4; ++kt) {
      f16x8 af = *(const f16x8*)((char*)a2 + lr * 256 + (kt * 32 + lk * 8) * 2);
      f16x8 bf;
      #pragma unroll
      for (int j = 0; j < 8; ++j) bf[j] = w3s[(kt * 32 + lk * 8 + j) * 32 + n];
      acc3 = MFMA16(af, bf, acc3);
    }
    if (n < 30) {
      float bb = gdb3[n];
      #pragma unroll
      for (int r = 0; r < 4; ++r) {
        float v = sigm(acc3[r] + bb);
        gout[(size_t)(bg + lk * 4 + r) * 30 + n] = v;
      }
    }
  }
}

extern "C" void kernel_launch(void* const* d_in, const int* in_sizes, int n_in,
                              void* d_out, int out_size, void* d_ws, size_t ws_size,
                              hipStream_t stream) {
  (void)in_sizes; (void)n_in; (void)out_size;
  const size_t W1OFF = 35651584;             // z: 32768*544*2
  const size_t W2OFF = W1OFF + 278528;       // w1t
  const size_t W3OFF = W2OFF + 65536;        // w2t
  const size_t NEED  = W3OFF + 8192;         // w3t
  if (ws_size >= NEED) {
    f16* wzp = (f16*)d_ws;
    f16* w1t = (f16*)((char*)d_ws + W1OFF);
    f16* w2t = (f16*)((char*)d_ws + W2OFF);
    f16* w3t = (f16*)((char*)d_ws + W3OFF);
    hwq_prep<<<256, 256, 0, stream>>>((const float*)d_in[8], (const float*)d_in[10],
                                      (const float*)d_in[12], w1t, w2t, w3t);
    hwq_rec<<<GRID_REC, 256, 0, stream>>>(
        (const float*)d_in[0], (const float*)d_in[1], (const float*)d_in[2],
        (const float*)d_in[3], (const float*)d_in[4], (const float*)d_in[5],
        (const float*)d_in[6], (const float*)d_in[7], wzp);
    hwq_dec<<<512, 256, 0, stream>>>(wzp, w1t, w2t, w3t,
                                     (const float*)d_in[9], (const float*)d_in[11],
                                     (const float*)d_in[13], (float*)d_out);
  } else {
    hwq_fused_mono<<<2048, 256, 0, stream>>>(
        (const float*)d_in[0],  (const float*)d_in[1],  (const float*)d_in[2],
        (const float*)d_in[3],  (const float*)d_in[4],  (const float*)d_in[5],
        (const float*)d_in[6],  (const float*)d_in[7],  (const float*)d_in[8],
        (const float*)d_in[9],  (const float*)d_in[10], (const float*)d_in[11],
        (const float*)d_in[12], (const float*)d_in[13], (float*)d_out);
  }
}

// Round 11
// 604.475 us; speedup vs baseline: 2.4230x; 1.0473x over previous
//
#include <hip/hip_runtime.h>

typedef _Float16 f16;
typedef _Float16 f16x4 __attribute__((ext_vector_type(4)));
typedef _Float16 f16x8 __attribute__((ext_vector_type(8)));
typedef float f32x2 __attribute__((ext_vector_type(2)));
typedef float f32x4 __attribute__((ext_vector_type(4)));

#define MFMA16(a, b, c) __builtin_amdgcn_mfma_f32_16x16x32_f16((a), (b), (c), 0, 0, 0)

__device__ __forceinline__ float rcp_(float x) { return __builtin_amdgcn_rcpf(x); }
__device__ __forceinline__ float sigm(float v) { return rcp_(1.0f + __expf(-v)); }
__device__ __forceinline__ float tanh_(float v) { return 1.0f - 2.0f * rcp_(__expf(2.0f * v) + 1.0f); }
__device__ __forceinline__ float exp2_(float x) { return __builtin_amdgcn_exp2f(x); }

// ============ Kernel A: persistent ConvLSTM recurrence (all-register A) ========
// R17 vs R16 (633 us total: rec ~576, MfmaUtil 46, Occ 33.5):
//  * t=0 PEELED to an x-only path: h==0 at t=0, so the 9 tap-GEMMs (144 of
//    176 MFMAs/wave) multiplied zeros. Saves 6.8% of rec MFMA + 72 b128/wave.
//    This also makes per-group hpad interior zeroing dead (t=0 never reads
//    hpad; all later reads preceded by writes; ring zeroed once in prologue).
//  * hwq_dec re-tiled 64->32 rows/block (grid 1024, LDS 27KB, lb(256,4)):
//    was 7x off roofline (latency-bound at 8 waves/CU); more blocks/CU.
//
// Arena: hpad[2] [4 b][36 cell][80 B] 0..23040 (cell 80 B, sample 2880 B)
//        xpad[2] [4 b][36 cell][8 B]  23040..25344
#define LOG2E 1.4426950408889634f
#define HCELL 80
#define HSAMP 2880
#define HBUFB 11520
#define XP0 23040
#define XBUFB 1152
#define AR 25344
#define WSO 25344
#define SMEMA 50688
#define NPAIR 4096
#define GRID_REC 768

extern "C" __global__ __launch_bounds__(256, 3)
void hwq_rec(const float* __restrict__ gx, const float* __restrict__ ghour,
             const float* __restrict__ gcw, const float* __restrict__ gcb,
             const float* __restrict__ ghw1, const float* __restrict__ ghb1,
             const float* __restrict__ ghw2, const float* __restrict__ ghb2,
             f16* __restrict__ wz)
{
  __shared__ __align__(16) char smem[SMEMA];
  const int tid = threadIdx.x;
  const int lane = tid & 63;
  const int wv = tid >> 6;              // M-chunk: rows [wv*32, wv*32+32)
  const int lr = lane & 15;
  const int lk = lane >> 4;
  const int TOFF[9] = {0, 1, 2, 6, 7, 8, 12, 13, 14};
  const int pp0 = (lr >> 2) * 6 + (lr & 3);

  // ---- prologue 1 (WS = arena B space, used BEFORE arenas are zeroed):
  //      stage scaled Ax1 table [128 m][32 k]; gather Ax1; Ax2 direct ----
  f16x8 Ax1[2], Ax2[2];
  {
    f16* axs = (f16*)(smem + WSO);
    for (int i = tid; i < 4096; i += 256) {
      int m = i >> 5, k = i & 31;
      int tau = k >> 2, sl = k & 3;
      int oc = ((m & 3) << 5) + (m >> 2);
      float sc = ((m & 3) == 3) ? (2.0f * LOG2E) : (-LOG2E);
      f16 v = (f16)0.0f;
      if (sl < 3) v = (f16)(sc * gcw[oc * 315 + sl * 9 + tau]);
      else if (tau == 4) v = (f16)(sc * gcb[oc]);
      axs[i] = v;
    }
    __syncthreads();
    #pragma unroll
    for (int mt = 0; mt < 2; ++mt) {
      Ax1[mt] = *(const f16x8*)(smem + WSO + (wv * 32 + mt * 16 + lr) * 64 + lk * 16);
      int m = wv * 32 + mt * 16 + lr;
      int oc = ((m & 3) << 5) + (m >> 2);
      float sc = ((m & 3) == 3) ? (2.0f * LOG2E) : (-LOG2E);
      f16x8 f = {(f16)0, (f16)0, (f16)0, (f16)0, (f16)0, (f16)0, (f16)0, (f16)0};
      if (lk == 0) {
        f[0] = (f16)(sc * gcw[oc * 315 + 8]);
        f[1] = (f16)(sc * gcw[oc * 315 + 17]);
        f[2] = (f16)(sc * gcw[oc * 315 + 26]);
      }
      Ax2[mt] = f;
    }
    __syncthreads();
  }
  // ---- prologue 2: 9 tap A-frags for this wave's 32 rows via 4 staged chunks
  f16x8 Ah[9][2];
  {
    f16* wst = (f16*)(smem + WSO);   // [32 row][288 = ch*9+tap]
    #pragma unroll
    for (int c = 0; c < 4; ++c) {
      for (int i = tid; i < 9216; i += 256) {
        int mrow = i / 288, rem = i - mrow * 288;
        int m = c * 32 + mrow;
        int oc = ((m & 3) << 5) + (m >> 2);
        float sc = ((m & 3) == 3) ? (2.0f * LOG2E) : (-LOG2E);
        wst[i] = (f16)(sc * gcw[oc * 315 + 27 + rem]);
      }
      __syncthreads();
      if (wv == c) {
        #pragma unroll
        for (int mt = 0; mt < 2; ++mt) {
          #pragma unroll
          for (int tap = 0; tap < 9; ++tap) {
            f16x8 f;
            #pragma unroll
            for (int j = 0; j < 8; ++j)
              f[j] = wst[(mt * 16 + lr) * 288 + (lk * 8 + j) * 9 + tap];
            Ah[tap][mt] = f;
          }
        }
      }
      __syncthreads();
    }
  }
  // ---- prologue 3: zero BOTH arenas (over WS); bias flags in all 4 xpads ----
  {
    float* za = (float*)smem;
    for (int i = tid; i < 12672; i += 256) za[i] = 0.0f;   // 50688 B
    __syncthreads();
    {
      int ar = tid >> 7, xb = (tid >> 6) & 1, b = (tid >> 4) & 3, p = tid & 15;
      int cell = ((p >> 2) + 1) * 6 + (p & 3) + 1;
      *(f16*)(smem + ar * AR + XP0 + xb * XBUFB + b * 288 + cell * 8 + 6) = (f16)1.0f;
    }
    __syncthreads();
  }

  // ---- hot-loop bases (arena-relative, pair-invariant) ----
  const int hb  = pp0 * HCELL + lk * 16;                     // + nt*HSAMP
  const int xpb = XP0 + pp0 * 8;                             // + nt*288
  const int wb  = (pp0 + 7) * HCELL + (wv * 8 + lk) * 2;     // + nt*HSAMP + mt*8
  const int xo0 = TOFF[2 * lk] * 8;
  const int xo1 = TOFF[2 * lk + 1] * 8;
  const bool stg = tid < 192;
  const int sb = tid / 48, srem = tid - sb * 48;
  const int sp = srem & 15, sic = srem >> 4;
  const int xdst = XP0 + sb * 288 + (((sp >> 2) + 1) * 6 + (sp & 3) + 1) * 8 + sic * 2;

  const f32x4 Z0v = {0.f, 0.f, 0.f, 0.f};

// x+bias MFMAs, chain start (C = zero quad); ab = arena byte offset
#define XPH(ab, nt) { \
    const int base_ = (ab) + xrb + xpb + (nt) * 288; \
    f16x4 lo_ = *(const f16x4*)(smem + base_ + xo0); \
    f16x4 hi_ = *(const f16x4*)(smem + base_ + xo1); \
    f16x8 bf1_ = __builtin_shufflevector(lo_, hi_, 0, 1, 2, 3, 4, 5, 6, 7); \
    f16x4 l8_ = *(const f16x4*)(smem + base_ + 112); \
    f16x8 bf2_ = __builtin_shufflevector(l8_, l8_, 0, 1, 2, 3, 0, 1, 2, 3); \
    _Pragma("unroll") for (int mt = 0; mt < 2; ++mt) { \
      acc[mt][nt] = MFMA16(Ax1[mt], bf1_, Z0v); \
      acc[mt][nt] = MFMA16(Ax2[mt], bf2_, acc[mt][nt]); } }

// all 9 tap-GEMMs for one nt
#define TAPS(ab, nt) \
    _Pragma("unroll") for (int tap = 0; tap < 9; ++tap) { \
      f16x8 bf_ = *(const f16x8*)(smem + (ab) + rb + hb + (nt) * HSAMP + TOFF[tap] * HCELL); \
      _Pragma("unroll") for (int mt = 0; mt < 2; ++mt) \
        acc[mt][nt] = MFMA16(Ah[tap][mt], bf_, acc[mt][nt]); }

#define PRIO1 __builtin_amdgcn_s_setprio(1)
#define PRIO0 __builtin_amdgcn_s_setprio(0)

// cell update, h -> LDS (other buffer). acc pre-scaled: (i,f,o)*-log2e, g*2log2e.
#define UPD_L(g, ab, mt, nt) { \
    float Ei = exp2_(acc[mt][nt][0]); \
    float Ef = exp2_(acc[mt][nt][1]); \
    float Eo = exp2_(acc[mt][nt][2]); \
    float Eg = exp2_(acc[mt][nt][3]); \
    float fg = rcp_(1.0f + Ef); \
    float pq = rcp_((1.0f + Ei) * (1.0f + Eg)); \
    float cn = fmaf(fg, cst[g][mt][nt], (2.0f * LOG2E) * ((Eg - 1.0f) * pq)); \
    cst[g][mt][nt] = cn; \
    float Ec = exp2_(cn); \
    *(f16*)(smem + (ab) + wbuf + wb + (nt) * HSAMP + (mt) * 8) = \
        (f16)((Ec - 1.0f) * rcp_((1.0f + Eo) * (1.0f + Ec))); }

// cell update, h -> global wz (t = 11)
#define UPD_G(g, bgv, mt, nt) { \
    float Ei = exp2_(acc[mt][nt][0]); \
    float Ef = exp2_(acc[mt][nt][1]); \
    float Eo = exp2_(acc[mt][nt][2]); \
    float Eg = exp2_(acc[mt][nt][3]); \
    float fg = rcp_(1.0f + Ef); \
    float pq = rcp_((1.0f + Ei) * (1.0f + Eg)); \
    float cn = fmaf(fg, cst[g][mt][nt], (2.0f * LOG2E) * ((Eg - 1.0f) * pq)); \
    float Ec = exp2_(cn); \
    wz[(size_t)((bgv) + (nt)) * 544 + (wv * 8 + (mt) * 4 + lk) * 16 + lr] = \
        (f16)((Ec - 1.0f) * rcp_((1.0f + Eo) * (1.0f + Ec))); }

  // balanced contiguous partition: 4096 = 768*5 + 256
  const int bid = blockIdx.x;
  const int q_ = NPAIR / GRID_REC;                    // 5
  const int r_ = NPAIR - q_ * GRID_REC;               // 256
  const int myn = q_ + (bid < r_ ? 1 : 0);
  const int mys = (bid < r_) ? bid * (q_ + 1) : r_ * (q_ + 1) + (bid - r_) * q_;

  for (int pi = 0; pi < myn; ++pi) {
    const int pr = mys + pi;
    const int bgA = pr << 3;          // samples bgA..bgA+3
    const int bgB = bgA + 4;          // samples bgB..bgB+3
    const float* xsrcA = gx + (size_t)(bgA + sb) * 576 + srem;
    const float* xsrcB = gx + (size_t)(bgB + sb) * 576 + srem;

    // pair re-init: stage xpad0(t=0), cst = 0. (No hpad zeroing needed: the
    // peeled t=0 never reads hpad; later reads are write-preceded; ring is
    // zeroed once in prologue 3.)
    if (stg) {
      *(f16*)(smem + xdst) = (f16)xsrcA[0];
      *(f16*)(smem + AR + xdst) = (f16)xsrcB[0];
    }
    float cst[2][2][4];
    #pragma unroll
    for (int g = 0; g < 2; ++g)
      #pragma unroll
      for (int mt = 0; mt < 2; ++mt)
        #pragma unroll
        for (int nt = 0; nt < 4; ++nt) cst[g][mt][nt] = 0.0f;
    __syncthreads();   // xpad0 staged; also orders prev epilogue buf1 reads

    // ---- t = 0 peeled: h == 0 -> x-path only (32 MFMAs vs 176) ----
    {
      const int xrb  = 0;
      const int wbuf = HBUFB;          // write buf1
      float xvA = 0.0f, xvB = 0.0f;
      if (stg) { xvA = xsrcA[48]; xvB = xsrcB[48]; }

      f32x4 acc[2][4];
      PRIO1;
      XPH(0, 0); XPH(0, 1); XPH(0, 2); XPH(0, 3);
      XPH(AR, 0); XPH(AR, 1); XPH(AR, 2); XPH(AR, 3);
      PRIO0;
      UPD_L(0, 0, 0, 0); UPD_L(0, 0, 1, 0);
      UPD_L(0, 0, 0, 1); UPD_L(0, 0, 1, 1);
      UPD_L(0, 0, 0, 2); UPD_L(0, 0, 1, 2);
      UPD_L(0, 0, 0, 3); UPD_L(0, 0, 1, 3);
      UPD_L(1, AR, 0, 0); UPD_L(1, AR, 1, 0);
      UPD_L(1, AR, 0, 1); UPD_L(1, AR, 1, 1);
      UPD_L(1, AR, 0, 2); UPD_L(1, AR, 1, 2);
      UPD_L(1, AR, 0, 3); UPD_L(1, AR, 1, 3);

      if (stg) {
        *(f16*)(smem + XBUFB + xdst) = (f16)xvA;
        *(f16*)(smem + AR + XBUFB + xdst) = (f16)xvB;
      }
      __syncthreads();
    }

    for (int t = 1; t < 11; ++t) {
      const int rb   = (t & 1) * HBUFB;      // read buffer
      const int xrb  = (t & 1) * XBUFB;
      const int wbuf = HBUFB - rb;
      float xvA = 0.0f, xvB = 0.0f;
      if (stg) { xvA = xsrcA[(t + 1) * 48]; xvB = xsrcB[(t + 1) * 48]; }

      f32x4 acc[2][4];
      // ---- group A: full MFMA phase (4 nt chains) ----
      PRIO1;
      XPH(0, 0); TAPS(0, 0);
      XPH(0, 1); TAPS(0, 1);
      XPH(0, 2); TAPS(0, 2);
      XPH(0, 3); TAPS(0, 3);
      PRIO0;
      // A updates interleave with B's refill of the freed acc quads
      UPD_L(0, 0, 0, 0); UPD_L(0, 0, 1, 0);
      PRIO1; XPH(AR, 0); TAPS(AR, 0); PRIO0;
      UPD_L(0, 0, 0, 1); UPD_L(0, 0, 1, 1);
      PRIO1; XPH(AR, 1); TAPS(AR, 1); PRIO0;
      UPD_L(0, 0, 0, 2); UPD_L(0, 0, 1, 2);
      PRIO1; XPH(AR, 2); TAPS(AR, 2); PRIO0;
      UPD_L(0, 0, 0, 3); UPD_L(0, 0, 1, 3);
      PRIO1; XPH(AR, 3); TAPS(AR, 3); PRIO0;
      UPD_L(1, AR, 0, 0); UPD_L(1, AR, 1, 0);
      UPD_L(1, AR, 0, 1); UPD_L(1, AR, 1, 1);
      UPD_L(1, AR, 0, 2); UPD_L(1, AR, 1, 2);
      UPD_L(1, AR, 0, 3); UPD_L(1, AR, 1, 3);

      if (stg) {
        *(f16*)(smem + (XBUFB - xrb) + xdst) = (f16)xvA;
        *(f16*)(smem + AR + (XBUFB - xrb) + xdst) = (f16)xvB;
      }
      __syncthreads();   // ONE barrier per double t-step
    }

    // ---- t = 11 epilogue: reads buf1, writes wz; no trailing barrier needed
    {
      const int rb  = HBUFB;
      const int xrb = XBUFB;
      f32x4 acc[2][4];
      PRIO1;
      XPH(0, 0); TAPS(0, 0);
      XPH(0, 1); TAPS(0, 1);
      XPH(0, 2); TAPS(0, 2);
      XPH(0, 3); TAPS(0, 3);
      PRIO0;
      UPD_G(0, bgA, 0, 0); UPD_G(0, bgA, 1, 0);
      PRIO1; XPH(AR, 0); TAPS(AR, 0); PRIO0;
      UPD_G(0, bgA, 0, 1); UPD_G(0, bgA, 1, 1);
      PRIO1; XPH(AR, 1); TAPS(AR, 1); PRIO0;
      UPD_G(0, bgA, 0, 2); UPD_G(0, bgA, 1, 2);
      PRIO1; XPH(AR, 2); TAPS(AR, 2); PRIO0;
      UPD_G(0, bgA, 0, 3); UPD_G(0, bgA, 1, 3);
      PRIO1; XPH(AR, 3); TAPS(AR, 3); PRIO0;
      UPD_G(1, bgB, 0, 0); UPD_G(1, bgB, 1, 0);
      UPD_G(1, bgB, 0, 1); UPD_G(1, bgB, 1, 1);
      UPD_G(1, bgB, 0, 2); UPD_G(1, bgB, 1, 2);
      UPD_G(1, bgB, 0, 3); UPD_G(1, bgB, 1, 3);

      {
        int b = tid >> 5, k2 = tid & 31;     // b in 0..7 -> 8 samples
        int smp = bgA + b;                   // bgB = bgA+4 -> contiguous
        float h0 = ghour[smp];
        float a = ghb2[k2];
        #pragma unroll
        for (int ii = 0; ii < 16; ++ii) {
          float u = fmaxf(h0 * ghw1[ii] + ghb1[ii], 0.0f);
          a += u * ghw2[ii * 32 + k2];
        }
        wz[(size_t)smp * 544 + 512 + k2] = (f16)a;
      }
    }
  }
#undef XPH
#undef TAPS
#undef UPD_L
#undef UPD_G
#undef PRIO1
#undef PRIO0
}

// ======================= prep: weight transpose fp32->f16 =======================
extern "C" __global__ void hwq_prep(const float* __restrict__ gdw1,
                                    const float* __restrict__ gdw2,
                                    const float* __restrict__ gdw3,
                                    f16* __restrict__ w1t, f16* __restrict__ w2t,
                                    f16* __restrict__ w3t)
{
  int i0 = blockIdx.x * 256 + threadIdx.x;
  int stride = gridDim.x * 256;
  for (int idx = i0; idx < 139264; idx += stride) {
    int n = idx / 544, k = idx - n * 544;
    w1t[idx] = (f16)gdw1[k * 256 + n];
  }
  for (int idx = i0; idx < 32768; idx += stride) {
    int n = idx >> 8, k = idx & 255;
    w2t[idx] = (f16)gdw2[k * 128 + n];
  }
  for (int idx = i0; idx < 4096; idx += stride) {
    int n = idx >> 7, k = idx & 127;
    w3t[idx] = (n < 30) ? (f16)gdw3[k * 30 + n] : (f16)0.0f;
  }
}

// ======================= Kernel B: decoder MLP (32 rows/block) =======================
extern "C" __global__ __launch_bounds__(256, 4)
void hwq_dec(const f16* __restrict__ wz, const f16* __restrict__ w1t,
             const f16* __restrict__ w2t, const f16* __restrict__ w3t,
             const float* __restrict__ gdb1, const float* __restrict__ gdb2,
             const float* __restrict__ gdb3, float* __restrict__ gout)
{
  __shared__ __align__(16) char smem[27648];
  f16* a1 = (f16*)smem;               // [32][280]
  f16* a2 = (f16*)(smem + 17920);     // [32][152]
  const int tid = threadIdx.x;
  const int lane = tid & 63;
  const int wv = tid >> 6;
  const int lr = lane & 15;
  const int lk = lane >> 4;
  const int s0 = blockIdx.x << 5;

  f32x4 acc1[2][4];
  #pragma unroll
  for (int nt = 0; nt < 4; ++nt) {
    float bb = gdb1[wv * 64 + nt * 16 + lr];
    f32x4 bv = {bb, bb, bb, bb};
    #pragma unroll
    for (int mt = 0; mt < 2; ++mt) acc1[mt][nt] = bv;
  }
  for (int kt = 0; kt < 17; ++kt) {
    f16x8 af[2];
    #pragma unroll
    for (int mt = 0; mt < 2; ++mt)
      af[mt] = *(const f16x8*)(wz + (size_t)(s0 + mt * 16 + lr) * 544 + kt * 32 + lk * 8);
    #pragma unroll
    for (int nt = 0; nt < 4; ++nt) {
      f16x8 bf = *(const f16x8*)(w1t + (size_t)(wv * 64 + nt * 16 + lr) * 544 + kt * 32 + lk * 8);
      #pragma unroll
      for (int mt = 0; mt < 2; ++mt)
        acc1[mt][nt] = MFMA16(af[mt], bf, acc1[mt][nt]);
    }
  }
  #pragma unroll
  for (int mt = 0; mt < 2; ++mt)
    #pragma unroll
    for (int nt = 0; nt < 4; ++nt) {
      int n = wv * 64 + nt * 16 + lr;
      #pragma unroll
      for (int r = 0; r < 4; ++r)
        a1[(mt * 16 + lk * 4 + r) * 280 + n] = (f16)fmaxf(acc1[mt][nt][r], 0.0f);
    }
  __syncthreads();

  f32x4 acc2[2][2];
  #pragma unroll
  for (int nt = 0; nt < 2; ++nt) {
    float bb = gdb2[wv * 32 + nt * 16 + lr];
    f32x4 bv = {bb, bb, bb, bb};
    #pragma unroll
    for (int mt = 0; mt < 2; ++mt) acc2[mt][nt] = bv;
  }
  for (int kt = 0; kt < 8; ++kt) {
    f16x8 af[2];
    #pragma unroll
    for (int mt = 0; mt < 2; ++mt)
      af[mt] = *(const f16x8*)(a1 + (mt * 16 + lr) * 280 + kt * 32 + lk * 8);
    #pragma unroll
    for (int nt = 0; nt < 2; ++nt) {
      f16x8 bf = *(const f16x8*)(w2t + (size_t)(wv * 32 + nt * 16 + lr) * 256 + kt * 32 + lk * 8);
      #pragma unroll
      for (int mt = 0; mt < 2; ++mt)
        acc2[mt][nt] = MFMA16(af[mt], bf, acc2[mt][nt]);
    }
  }
  __syncthreads();
  #pragma unroll
  for (int mt = 0; mt < 2; ++mt)
    #pragma unroll
    for (int nt = 0; nt < 2; ++nt) {
      int n = wv * 32 + nt * 16 + lr;
      #pragma unroll
      for (int r = 0; r < 4; ++r)
        a2[(mt * 16 + lk * 4 + r) * 152 + n] = (f16)fmaxf(acc2[mt][nt][r], 0.0f);
    }
  __syncthreads();

  if (wv < 2) {
    int n = wv * 16 + lr;
    float bb = (n < 30) ? gdb3[n] : 0.0f;
    f32x4 acc3[2];
    #pragma unroll
    for (int mt = 0; mt < 2; ++mt) { f32x4 bv = {bb, bb, bb, bb}; acc3[mt] = bv; }
    #pragma unroll
    for (int kt = 0; kt < 4; ++kt) {
      f16x8 bf = *(const f16x8*)(w3t + n * 128 + kt * 32 + lk * 8);
      #pragma unroll
      for (int mt = 0; mt < 2; ++mt) {
        f16x8 af = *(const f16x8*)(a2 + (mt * 16 + lr) * 152 + kt * 32 + lk * 8);
        acc3[mt] = MFMA16(af, bf, acc3[mt]);
      }
    }
    if (n < 30) {
      #pragma unroll
      for (int mt = 0; mt < 2; ++mt)
        #pragma unroll
        for (int r = 0; r < 4; ++r)
          gout[(size_t)(s0 + mt * 16 + lk * 4 + r) * 30 + n] = sigm(acc3[mt][r]);
    }
  }
}

// ======================= Fallback: monolithic kernel (R1) =======================
typedef _Float16 f16x4m __attribute__((ext_vector_type(4)));
#define OFF_B 46080
#define SMEM_BYTES (46080 + 17408)

extern "C" __global__ __launch_bounds__(256, 1)
void hwq_fused_mono(const float* __restrict__ gx, const float* __restrict__ ghour,
               const float* __restrict__ gcw, const float* __restrict__ gcb,
               const float* __restrict__ ghw1, const float* __restrict__ ghb1,
               const float* __restrict__ ghw2, const float* __restrict__ ghb2,
               const float* __restrict__ gdw1, const float* __restrict__ gdb1,
               const float* __restrict__ gdw2, const float* __restrict__ gdb2,
               const float* __restrict__ gdw3, const float* __restrict__ gdb3,
               float* __restrict__ gout)
{
  __shared__ __align__(16) char smem[SMEM_BYTES];
  const int tid = threadIdx.x;
  const int lane = tid & 63;
  const int wv = tid >> 6;
  const int mg = wv & 1;
  const int ng = wv >> 1;
  const int lr = lane & 15;
  const int lk = lane >> 4;
  const int bg = blockIdx.x << 4;

  f16x8 Ah[9][4];
  {
    f16* wst = (f16*)(smem);
    #pragma unroll
    for (int c = 0; c < 2; ++c) {
      __syncthreads();
      for (int i = tid; i < 18432; i += 256) {
        int oc = i / 288, rem = i - oc * 288;
        wst[i] = (f16)gcw[(c * 64 + oc) * 315 + 27 + rem];
      }
      __syncthreads();
      #pragma unroll
      for (int g = 0; g < 2; ++g) {
        int ocl = g * 32 + mg * 16 + lr;
        #pragma unroll
        for (int tap = 0; tap < 9; ++tap) {
          f16x8 f;
          #pragma unroll
          for (int j = 0; j < 8; ++j)
            f[j] = wst[ocl * 288 + (lk * 8 + j) * 9 + tap];
          Ah[tap][c * 2 + g] = f;
        }
      }
    }
  }
  f16x8 Ax[4];
  {
    f16* xw = (f16*)(smem + OFF_B);
    __syncthreads();
    for (int i = tid; i < 3456; i += 256) {
      int oc = i / 27, rem = i - oc * 27;
      xw[i] = (f16)gcw[oc * 315 + rem];
    }
    __syncthreads();
    #pragma unroll
    for (int mt = 0; mt < 4; ++mt) {
      int oc = mt * 32 + mg * 16 + lr;
      f16x8 f;
      #pragma unroll
      for (int j = 0; j < 8; ++j) {
        int k = lk * 8 + j;
        int tap = (k * 11) >> 5;
        int ic = k - 3 * tap;
        f16 v = (f16)0.0f;
        if (k < 27) v = xw[oc * 27 + ic * 9 + tap];
        f[j] = v;
      }
      Ax[mt] = f;
    }
    __syncthreads();
  }

  float bias[4][4];
  #pragma unroll
  for (int mt = 0; mt < 4; ++mt)
    #pragma unroll
    for (int r = 0; r < 4; ++r)
      bias[mt][r] = gcb[mt * 32 + mg * 16 + lk * 4 + r];

  {
    float* za = (float*)smem;
    for (int i = tid; i < 11520; i += 256) za[i] = 0.0f;
    float* zb = (float*)(smem + OFF_B);
    for (int i = tid; i < 1152; i += 256) zb[i] = 0.0f;
    __syncthreads();
    for (int i = tid; i < 768; i += 256) {
      int b = i / 48, rem = i - b * 48;
      int pos = rem & 15;
      int ic = rem >> 4;
      int pp = (pos >> 2) * 6 + (pos & 3) + 7;
      *(f16*)(smem + OFF_B + b * 288 + pp * 8 + ic * 2) =
          (f16)gx[(size_t)(bg + b) * 576 + rem];
    }
    __syncthreads();
  }

  int hbase[8], xbase[8], wbase[8];
  #pragma unroll
  for (int nt = 0; nt < 8; ++nt) {
    int n = ng * 128 + nt * 16 + lr;
    int b = n >> 4, pos = n & 15;
    int pp0 = (pos >> 2) * 6 + (pos & 3);
    hbase[nt] = b * 2880 + pp0 * 80 + lk * 16;
    xbase[nt] = OFF_B + b * 288 + pp0 * 8;
    wbase[nt] = b * 2880 + (pp0 + 7) * 80 + (mg * 16 + lk * 4) * 2;
  }
  int xoff[8], xval[8];
  #pragma unroll
  for (int j = 0; j < 8; ++j) {
    int k = lk * 8 + j;
    int tap = (k * 11) >> 5;
    int ic = k - 3 * tap;
    xoff[j] = ((tap / 3) * 6 + (tap % 3)) * 8 + ic * 2;
    xval[j] = (k < 27);
  }

  const int TOFF[9] = {0, 1, 2, 6, 7, 8, 12, 13, 14};

  f32x4 cst[8];
  #pragma unroll
  for (int nt = 0; nt < 8; ++nt) { f32x4 z = {0.f, 0.f, 0.f, 0.f}; cst[nt] = z; }

  for (int t = 0; t < 12; ++t) {
    f32x4 acc[4][8];
    #pragma unroll
    for (int mt = 0; mt < 4; ++mt) {
      f32x4 bi = {bias[mt][0], bias[mt][1], bias[mt][2], bias[mt][3]};
      #pragma unroll
      for (int nt = 0; nt < 8; ++nt) acc[mt][nt] = bi;
    }
    #pragma unroll
    for (int tap = 0; tap < 9; ++tap) {
      #pragma unroll
      for (int nt = 0; nt < 8; ++nt) {
        f16x8 bf = *(const f16x8*)(smem + hbase[nt] + TOFF[tap] * 80);
        #pragma unroll
        for (int mt = 0; mt < 4; ++mt)
          acc[mt][nt] = MFMA16(Ah[tap][mt], bf, acc[mt][nt]);
      }
    }
    #pragma unroll
    for (int nt = 0; nt < 8; ++nt) {
      f16x8 bf;
      #pragma unroll
      for (int j = 0; j < 8; ++j) {
        int a = xval[j] ? (xbase[nt] + xoff[j]) : OFF_B;
        bf[j] = *(const f16*)(smem + a);
      }
      #pragma unroll
      for (int mt = 0; mt < 4; ++mt)
        acc[mt][nt] = MFMA16(Ax[mt], bf, acc[mt][nt]);
    }
    __syncthreads();

    #pragma unroll
    for (int nt = 0; nt < 8; ++nt) {
      f16 hh[4];
      #pragma unroll
      for (int r = 0; r < 4; ++r) {
        float ig = sigm(acc[0][nt][r]);
        float fg = sigm(acc[1][nt][r]);
        float og = sigm(acc[2][nt][r]);
        float gg = tanh_(acc[3][nt][r]);
        float cn = fg * cst[nt][r] + ig * gg;
        cst[nt][r] = cn;
        hh[r] = (f16)(og * tanh_(cn));
      }
      if (t < 11) {
        f16x4m hv = {hh[0], hh[1], hh[2], hh[3]};
        *(f16x4m*)(smem + wbase[nt]) = hv;
      } else {
        int n = ng * 128 + nt * 16 + lr;
        int b = n >> 4, pos = n & 15;
        int ch0 = mg * 16 + lk * 4;
        #pragma unroll
        for (int r = 0; r < 4; ++r)
          *(f16*)(smem + OFF_B + b * 1088 + (ch0 + r) * 32 + pos * 2) = hh[r];
      }
    }
    if (t < 11) {
      for (int i = tid; i < 768; i += 256) {
        int b = i / 48, rem = i - b * 48;
        int pos = rem & 15;
        int ic = rem >> 4;
        int pp = (pos >> 2) * 6 + (pos & 3) + 7;
        *(f16*)(smem + OFF_B + b * 288 + pp * 8 + ic * 2) =
            (f16)gx[(size_t)(bg + b) * 576 + (t + 1) * 48 + rem];
      }
    } else {
      for (int i = tid; i < 512; i += 256) {
        int b = i >> 5, k2 = i & 31;
        float h0 = ghour[bg + b];
        float a = ghb2[k2];
        #pragma unroll
        for (int ii = 0; ii < 16; ++ii) {
          float u = fmaxf(h0 * ghw1[ii] + ghb1[ii], 0.0f);
          a += u * ghw2[ii * 32 + k2];
        }
        *(f16*)(smem + OFF_B + b * 1088 + (512 + k2) * 2) = (f16)a;
      }
    }
    __syncthreads();
  }

  f16* zz  = (f16*)(smem + OFF_B);
  f16* wch = (f16*)(smem);
  f16* a1  = (f16*)(smem + 16384);
  f16* a2  = (f16*)(smem + 24576);
  f16* w3s = (f16*)(smem + 28672);

  f32x4 acc1[4];
  #pragma unroll
  for (int i = 0; i < 4; ++i) { f32x4 z = {0.f, 0.f, 0.f, 0.f}; acc1[i] = z; }
  for (int kt = 0; kt < 17; ++kt) {
    __syncthreads();
    for (int i = tid; i < 8192; i += 256) {
      int k = i >> 8, n = i & 255;
      wch[i] = (f16)gdw1[(kt * 32 + k) * 256 + n];
    }
    __syncthreads();
    f16x8 af = *(const f16x8*)((char*)zz + lr * 1088 + (kt * 32 + lk * 8) * 2);
    #pragma unroll
    for (int nt = 0; nt < 4; ++nt) {
      int n = (wv * 4 + nt) * 16 + lr;
      f16x8 bf;
      #pragma unroll
      for (int j = 0; j < 8; ++j) bf[j] = wch[(lk * 8 + j) * 256 + n];
      acc1[nt] = MFMA16(af, bf, acc1[nt]);
    }
  }
  __syncthreads();
  #pragma unroll
  for (int nt = 0; nt < 4; ++nt) {
    int n = (wv * 4 + nt) * 16 + lr;
    float bb = gdb1[n];
    #pragma unroll
    for (int r = 0; r < 4; ++r)
      a1[(lk * 4 + r) * 256 + n] = (f16)fmaxf(acc1[nt][r] + bb, 0.0f);
  }

  f32x4 acc2[2];
  #pragma unroll
  for (int i = 0; i < 2; ++i) { f32x4 z = {0.f, 0.f, 0.f, 0.f}; acc2[i] = z; }
  for (int kt = 0; kt < 8; ++kt) {
    __syncthreads();
    for (int i = tid; i < 4096; i += 256) {
      int k = i >> 7, n = i & 127;
      wch[i] = (f16)gdw2[(kt * 32 + k) * 128 + n];
    }
    __syncthreads();
    f16x8 af = *(const f16x8*)((char*)a1 + lr * 512 + (kt * 32 + lk * 8) * 2);
    #pragma unroll
    for (int nt = 0; nt < 2; ++nt) {
      int n = (wv * 2 + nt) * 16 + lr;
      f16x8 bf;
      #pragma unroll
      for (int j = 0; j < 8; ++j) bf[j] = wch[(lk * 8 + j) * 128 + n];
      acc2[nt] = MFMA16(af, bf, acc2[nt]);
    }
  }
  __syncthreads();
  #pragma unroll
  for (int nt = 0; nt < 2; ++nt) {
    int n = (wv * 2 + nt) * 16 + lr;
    float bb = gdb2[n];
    #pragma unroll
    for (int r = 0; r < 4; ++r)
      a2[(lk * 4 + r) * 128 + n] = (f16)fmaxf(acc2[nt][r] + bb, 0.0f);
  }
  __syncthreads();

  for (int i = tid; i < 4096; i += 256) {
    int k = i >> 5, n = i & 31;
    w3s[i] = (n < 30) ? (f16)gdw3[k * 30 + n] : (f16)0.0f;
  }
  __syncthreads();
  if (wv < 2) {
    f32x4 acc3 = {0.f, 0.f, 0.f, 0.f};
    int n = wv * 16 + lr;
    #pragma unroll
    for (int kt = 0; kt < 4; ++kt) {
      f16x8 af = *(const f16x8*)((char*)a2 + lr * 256 + (kt * 32 + lk * 8) * 2);
      f16x8 bf;
      #pragma unroll
      for (int j = 0; j < 8; ++j) bf[j] = w3s[(kt * 32 + lk * 8 + j) * 32 + n];
      acc3 = MFMA16(af, bf, acc3);
    }
    if (n < 30) {
      float bb = gdb3[n];
      #pragma unroll
      for (int r = 0; r < 4; ++r) {
        float v = sigm(acc3[r] + bb);
        gout[(size_t)(bg + lk * 4 + r) * 30 + n] = v;
      }
    }
  }
}

extern "C" void kernel_launch(void* const* d_in, const int* in_sizes, int n_in,
                              void* d_out, int out_size, void* d_ws, size_t ws_size,
                              hipStream_t stream) {
  (void)in_sizes; (void)n_in; (void)out_size;
  const size_t W1OFF = 35651584;             // z: 32768*544*2
  const size_t W2OFF = W1OFF + 278528;       // w1t
  const size_t W3OFF = W2OFF + 65536;        // w2t
  const size_t NEED  = W3OFF + 8192;         // w3t
  if (ws_size >= NEED) {
    f16* wzp = (f16*)d_ws;
    f16* w1t = (f16*)((char*)d_ws + W1OFF);
    f16* w2t = (f16*)((char*)d_ws + W2OFF);
    f16* w3t = (f16*)((char*)d_ws + W3OFF);
    hwq_prep<<<256, 256, 0, stream>>>((const float*)d_in[8], (const float*)d_in[10],
                                      (const float*)d_in[12], w1t, w2t, w3t);
    hwq_rec<<<GRID_REC, 256, 0, stream>>>(
        (const float*)d_in[0], (const float*)d_in[1], (const float*)d_in[2],
        (const float*)d_in[3], (const float*)d_in[4], (const float*)d_in[5],
        (const float*)d_in[6], (const float*)d_in[7], wzp);
    hwq_dec<<<1024, 256, 0, stream>>>(wzp, w1t, w2t, w3t,
                                      (const float*)d_in[9], (const float*)d_in[11],
                                      (const float*)d_in[13], (float*)d_out);
  } else {
    hwq_fused_mono<<<2048, 256, 0, stream>>>(
        (const float*)d_in[0],  (const float*)d_in[1],  (const float*)d_in[2],
        (const float*)d_in[3],  (const float*)d_in[4],  (const float*)d_in[5],
        (const float*)d_in[6],  (const float*)d_in[7],  (const float*)d_in[8],
        (const float*)d_in[9],  (const float*)d_in[10], (const float*)d_in[11],
        (const float*)d_in[12], (const float*)d_in[13], (float*)d_out);
  }
}